// Round 1
// baseline (35578.427 us; speedup 1.0000x reference)
//
#include <hip/hip_runtime.h>
#include <hip/hip_bf16.h>
#include <cstddef>

#define MM     281
#define NSEQ   33049
#define BB     4
#define NH     32768          // NSEQ - MM
#define NTOT   (BB*NSEQ)      // 132196
#define MPAD   288
#define NSPLIT 8
#define SCALEQ 0.125f
#define LORAS  2.0f

// ---------------- K0: fold LoRA + scales into combined weight matrix ----------------
// Wc rows: [0,128)=SCALE*(qW+2*qA@qB), [128,256)=k rows of kvW_eff, [256,384)=v rows,
//          [384,512)=res_w*resW.  bc = matching bias.
__global__ void k_weights(const float* __restrict__ qW, const float* __restrict__ qb,
                          const float* __restrict__ qA, const float* __restrict__ qB,
                          const float* __restrict__ kvW, const float* __restrict__ kvb,
                          const float* __restrict__ kvA, const float* __restrict__ kvB,
                          const float* __restrict__ resW, const float* __restrict__ resw,
                          float* __restrict__ Wc, float* __restrict__ bc){
  int j = blockIdx.x;     // 0..511
  int c = threadIdx.x;    // 0..255
  float w;
  if (j < 128){
    float l = 0.f;
    #pragma unroll
    for (int r = 0; r < 8; ++r) l += qA[j*8+r]*qB[r*256+c];
    w = SCALEQ*(qW[j*256+c] + LORAS*l);
    if (c==0) bc[j] = SCALEQ*qb[j];
  } else if (j < 384){
    int jj = j-128;
    float l = 0.f;
    #pragma unroll
    for (int r = 0; r < 8; ++r) l += kvA[jj*8+r]*kvB[r*256+c];
    w = kvW[jj*256+c] + LORAS*l;
    if (c==0) bc[j] = kvb[jj];
  } else {
    int jj = j-384;
    w = resw[0]*resW[jj*256+c];
    if (c==0) bc[j] = 0.f;
  }
  Wc[j*256+c] = w;
}

// ---------------- K1: fused projection GEMM  Y = x @ Wc.T + bc ----------------
// 64x64 tile, 256 threads, 4x4 micro-tile. Outputs scatter to Q/K/V ws and res->d_out.
__global__ __launch_bounds__(256) void k_proj(const float* __restrict__ X,
                       const float* __restrict__ Wc, const float* __restrict__ bc,
                       float* __restrict__ Q, float* __restrict__ K, float* __restrict__ V,
                       float* __restrict__ OUT){
  __shared__ __align__(16) float As[32][68];
  __shared__ __align__(16) float Bs[32][68];
  int tid = threadIdx.x;
  int rowBase = blockIdx.x*64;
  int jBase   = blockIdx.y*64;
  int tm = tid & 15, tn = tid >> 4;
  float acc[4][4];
  #pragma unroll
  for (int i=0;i<4;++i)
    #pragma unroll
    for (int j=0;j<4;++j) acc[i][j]=0.f;

  for (int k0 = 0; k0 < 256; k0 += 32){
    #pragma unroll
    for (int i = 0; i < 8; ++i){
      int lin = tid + 256*i;
      int m = lin >> 5, kk = lin & 31;
      int row = rowBase + m; if (row >= NTOT) row = NTOT-1;
      As[kk][m] = X[(size_t)row*256 + k0 + kk];
      Bs[kk][m] = Wc[(size_t)(jBase+m)*256 + k0 + kk];
    }
    __syncthreads();
    #pragma unroll
    for (int kk = 0; kk < 32; ++kk){
      float4 a = *(const float4*)&As[kk][tm*4];
      float4 b = *(const float4*)&Bs[kk][tn*4];
      acc[0][0]+=a.x*b.x; acc[0][1]+=a.x*b.y; acc[0][2]+=a.x*b.z; acc[0][3]+=a.x*b.w;
      acc[1][0]+=a.y*b.x; acc[1][1]+=a.y*b.y; acc[1][2]+=a.y*b.z; acc[1][3]+=a.y*b.w;
      acc[2][0]+=a.z*b.x; acc[2][1]+=a.z*b.y; acc[2][2]+=a.z*b.z; acc[2][3]+=a.z*b.w;
      acc[3][0]+=a.w*b.x; acc[3][1]+=a.w*b.y; acc[3][2]+=a.w*b.z; acc[3][3]+=a.w*b.w;
    }
    __syncthreads();
  }
  #pragma unroll
  for (int i=0;i<4;++i){
    int row = rowBase + tm*4 + i;
    if (row >= NTOT) continue;
    #pragma unroll
    for (int j=0;j<4;++j){
      int jj = jBase + tn*4 + j;
      float v = acc[i][j] + bc[jj];
      size_t o = (size_t)row*128;
      if      (jj < 128) Q[o + jj]       = v;
      else if (jj < 256) K[o + jj-128]   = v;
      else if (jj < 384) V[o + jj-256]   = v;
      else               OUT[o + jj-384] = v;
    }
  }
}

// ---------------- K2: flash attn_p partials (out_p accumulation, split over keys) ------
__global__ __launch_bounds__(256) void k_attnp(const float* __restrict__ Q,
                        const float* __restrict__ K, const float* __restrict__ V,
                        float* __restrict__ PACC, float* __restrict__ PMX,
                        float* __restrict__ PSM){
  __shared__ float qs[32][129];
  __shared__ float ks[64][129];
  __shared__ float vs[64][129];
  __shared__ float Ssh[32][65];
  int b = blockIdx.x, mt = blockIdx.y, s = blockIdx.z;
  int tid = threadIdx.x;
  int r = tid & 31, g = tid >> 5;   // r: m-row, g: d-slice of 16
  int m0 = mt*32;
  for (int i = tid; i < 32*128; i += 256){
    int rr = i >> 7, d = i & 127;
    int m = m0 + rr;
    qs[rr][d] = (m < MM) ? Q[((size_t)b*NSEQ + m)*128 + d] : 0.f;
  }
  __syncthreads();
  float acc[16];
  #pragma unroll
  for (int i=0;i<16;++i) acc[i]=0.f;
  float rmax = -1e30f, rsum = 0.f;
  int nnBase = s*(NH/NSPLIT);
  for (int c = 0; c < (NH/NSPLIT)/64; ++c){
    int nn0 = nnBase + c*64;
    for (int i = tid; i < 64*128; i += 256){
      int rr = i >> 7, d = i & 127;
      size_t gr = ((size_t)b*NSEQ + MM + nn0 + rr)*128 + d;
      ks[rr][d] = K[gr];
      vs[rr][d] = V[gr];
    }
    __syncthreads();
    float sc[8];
    #pragma unroll
    for (int i=0;i<8;++i) sc[i]=0.f;
    for (int d=0; d<128; ++d){
      float qd = qs[r][d];
      #pragma unroll
      for (int i=0;i<8;++i) sc[i] += qd*ks[g*8+i][d];
    }
    #pragma unroll
    for (int i=0;i<8;++i) Ssh[r][g*8+i] = sc[i];
    __syncthreads();
    float cmax = -1e30f;
    #pragma unroll
    for (int nn=0;nn<64;++nn) cmax = fmaxf(cmax, Ssh[r][nn]);
    float mnew = fmaxf(rmax, cmax);
    float scale = __expf(rmax - mnew);
    rsum *= scale;
    #pragma unroll
    for (int i=0;i<16;++i) acc[i] *= scale;
    for (int nn=0;nn<64;++nn){
      float w = __expf(Ssh[r][nn]-mnew);
      rsum += w;
      const float* vr = &vs[nn][g*16];
      #pragma unroll
      for (int i=0;i<16;++i) acc[i] += w*vr[i];
    }
    rmax = mnew;
    __syncthreads();
  }
  int m = m0 + r;
  size_t pb = (((size_t)b*NSPLIT + s)*MPAD + m);
  #pragma unroll
  for (int i=0;i<16;++i) PACC[pb*128 + g*16 + i] = acc[i];
  if (g == 0){ PMX[pb] = rmax; PSM[pb] = rsum; }
}

// ---------------- K3: combine attn_p splits -> out_p + final stats ----------------
__global__ void k_pcombine(const float* __restrict__ PACC, const float* __restrict__ PMX,
                           const float* __restrict__ PSM,
                           float* __restrict__ OP, float* __restrict__ PM,
                           float* __restrict__ PS){
  int b = blockIdx.x, m = blockIdx.y;   // m < 281
  int d = threadIdx.x;                  // 0..127
  float M = -1e30f;
  #pragma unroll
  for (int s=0;s<NSPLIT;++s) M = fmaxf(M, PMX[((size_t)b*NSPLIT+s)*MPAD+m]);
  float sum = 0.f, a = 0.f;
  #pragma unroll
  for (int s=0;s<NSPLIT;++s){
    size_t pb = ((size_t)b*NSPLIT+s)*MPAD+m;
    float e = __expf(PMX[pb]-M);
    sum += PSM[pb]*e;
    a   += PACC[pb*128+d]*e;
  }
  OP[((size_t)b*MPAD+m)*128+d] = a/sum;
  if (d==0){ PM[(size_t)b*MPAD+m]=M; PS[(size_t)b*MPAD+m]=sum; }
}

// ---------------- K4: attn_h fused: scores(16x281 in LDS) -> softmax -> out_h & xh ------
__global__ __launch_bounds__(256) void k_attnh(const float* __restrict__ Q,
                        const float* __restrict__ K, const float* __restrict__ V,
                        const float* __restrict__ OP,
                        float* __restrict__ OH, float* __restrict__ OUT){
  __shared__ float qs[16][129];
  __shared__ float S[16][289];
  __shared__ float stg[2][32][129];
  __shared__ float red[16][17];
  int b = blockIdx.x, t = blockIdx.y;
  int tid = threadIdx.x;
  int i0 = t*16;
  for (int i = tid; i < 16*128; i += 256){
    int rr = i >> 7, d = i & 127;
    qs[rr][d] = Q[((size_t)b*NSEQ + MM + i0 + rr)*128 + d];
  }
  __syncthreads();
  // phase a: all scores into LDS
  for (int mc = 0; mc < 9; ++mc){
    int mb = mc*32;
    for (int i = tid; i < 32*128; i += 256){
      int rr = i >> 7, d = i & 127;
      int m = mb + rr;
      stg[0][rr][d] = (m < MM) ? K[((size_t)b*NSEQ + m)*128 + d] : 0.f;
    }
    __syncthreads();
    #pragma unroll
    for (int half = 0; half < 2; ++half){
      int idx = tid + half*256;
      int rr = idx >> 5, mm = idx & 31;
      float sacc = 0.f;
      for (int d=0; d<128; ++d) sacc += qs[rr][d]*stg[0][mm][d];
      int m = mb + mm;
      S[rr][m] = (m < MM) ? sacc : -1e30f;
    }
    __syncthreads();
  }
  // phase b: row softmax over 288 (invalid entries are -1e30 -> 0)
  {
    int rr = tid >> 4, g = tid & 15;
    float lmax = -1e30f;
    for (int m = g; m < MPAD; m += 16) lmax = fmaxf(lmax, S[rr][m]);
    red[rr][g] = lmax;
    __syncthreads();
    if (g == 0){
      float M = -1e30f;
      #pragma unroll
      for (int i=0;i<16;++i) M = fmaxf(M, red[rr][i]);
      red[rr][16] = M;
    }
    __syncthreads();
    float M = red[rr][16];
    float lsum = 0.f;
    for (int m = g; m < MPAD; m += 16){
      float e = __expf(S[rr][m]-M);
      S[rr][m] = e;
      lsum += e;
    }
    __syncthreads();
    red[rr][g] = lsum;
    __syncthreads();
    if (g == 0){
      float sm = 0.f;
      #pragma unroll
      for (int i=0;i<16;++i) sm += red[rr][i];
      red[rr][16] = sm;
    }
    __syncthreads();
    float rinv = 1.f/red[rr][16];
    for (int m = g; m < MPAD; m += 16) S[rr][m] *= rinv;
  }
  __syncthreads();
  // phase c: out_h = P@v_p ; xh = P@out_p  (accumulate into d_out over res)
  {
    int rr = tid & 15, g = tid >> 4;  // rr: row, g: d-slice of 8
    float aoh[8], axh[8];
    #pragma unroll
    for (int i=0;i<8;++i){ aoh[i]=0.f; axh[i]=0.f; }
    for (int mc = 0; mc < 9; ++mc){
      int mb = mc*32;
      for (int i = tid; i < 32*128; i += 256){
        int r2 = i >> 7, d = i & 127;
        int m = mb + r2;
        stg[0][r2][d] = (m < MM) ? V [((size_t)b*NSEQ + m)*128 + d] : 0.f;
        stg[1][r2][d] = (m < MM) ? OP[((size_t)b*MPAD + m)*128 + d] : 0.f;
      }
      __syncthreads();
      for (int mm = 0; mm < 32; ++mm){
        float w = S[rr][mb+mm];
        #pragma unroll
        for (int i=0;i<8;++i){
          aoh[i] += w*stg[0][mm][g*8+i];
          axh[i] += w*stg[1][mm][g*8+i];
        }
      }
      __syncthreads();
    }
    size_t oh = ((size_t)b*NH + i0 + rr)*128 + g*8;
    #pragma unroll
    for (int i=0;i<8;++i) OH[oh+i] = aoh[i];
    size_t oo = ((size_t)b*NSEQ + MM + i0 + rr)*128 + g*8;
    #pragma unroll
    for (int i=0;i<8;++i) OUT[oo+i] += axh[i];
  }
}

// ---------------- K5: xp = attn_p @ out_h (recompute weights from stats), partials ------
__global__ __launch_bounds__(256) void k_xp(const float* __restrict__ Q,
                     const float* __restrict__ K, const float* __restrict__ OH,
                     const float* __restrict__ PM, const float* __restrict__ PS,
                     float* __restrict__ PACC){
  __shared__ float qs[32][129];
  __shared__ float ks[64][129];
  __shared__ float os[64][129];
  __shared__ float Ssh[32][65];
  int b = blockIdx.x, mt = blockIdx.y, s = blockIdx.z;
  int tid = threadIdx.x;
  int r = tid & 31, g = tid >> 5;
  int m0 = mt*32;
  for (int i = tid; i < 32*128; i += 256){
    int rr = i >> 7, d = i & 127;
    int m = m0 + rr;
    qs[rr][d] = (m < MM) ? Q[((size_t)b*NSEQ + m)*128 + d] : 0.f;
  }
  __syncthreads();
  int m = m0 + r;
  float pmax = (m < MM) ? PM[(size_t)b*MPAD+m] : 0.f;
  float rinv = (m < MM) ? 1.f/PS[(size_t)b*MPAD+m] : 0.f;
  float acc[16];
  #pragma unroll
  for (int i=0;i<16;++i) acc[i]=0.f;
  int nnBase = s*(NH/NSPLIT);
  for (int c = 0; c < (NH/NSPLIT)/64; ++c){
    int nn0 = nnBase + c*64;
    for (int i = tid; i < 64*128; i += 256){
      int rr = i >> 7, d = i & 127;
      ks[rr][d] = K [((size_t)b*NSEQ + MM + nn0 + rr)*128 + d];
      os[rr][d] = OH[((size_t)b*NH  +      nn0 + rr)*128 + d];
    }
    __syncthreads();
    float sc[8];
    #pragma unroll
    for (int i=0;i<8;++i) sc[i]=0.f;
    for (int d=0; d<128; ++d){
      float qd = qs[r][d];
      #pragma unroll
      for (int i=0;i<8;++i) sc[i] += qd*ks[g*8+i][d];
    }
    #pragma unroll
    for (int i=0;i<8;++i) Ssh[r][g*8+i] = sc[i];
    __syncthreads();
    for (int nn=0;nn<64;++nn){
      float w = __expf(Ssh[r][nn]-pmax);
      const float* orow = &os[nn][g*16];
      #pragma unroll
      for (int i=0;i<16;++i) acc[i] += w*orow[i];
    }
    __syncthreads();
  }
  size_t pb = (((size_t)b*NSPLIT + s)*MPAD + m);
  #pragma unroll
  for (int i=0;i<16;++i) PACC[pb*128 + g*16 + i] = acc[i]*rinv;
}

// ---------------- K6: deterministic reduction of xp partials into d_out ----------------
__global__ void k_xpreduce(const float* __restrict__ PACC, float* __restrict__ OUT){
  int b = blockIdx.x, m = blockIdx.y;   // m < 281
  int d = threadIdx.x;
  float a = 0.f;
  #pragma unroll
  for (int s=0;s<NSPLIT;++s) a += PACC[(((size_t)b*NSPLIT+s)*MPAD+m)*128+d];
  OUT[((size_t)b*NSEQ+m)*128+d] += a;
}

extern "C" void kernel_launch(void* const* d_in, const int* in_sizes, int n_in,
                              void* d_out, int out_size, void* d_ws, size_t ws_size,
                              hipStream_t stream){
  const float* x    = (const float*)d_in[0];
  const float* qW   = (const float*)d_in[1];
  const float* qb   = (const float*)d_in[2];
  const float* qA   = (const float*)d_in[3];
  const float* qB   = (const float*)d_in[4];
  const float* kvW  = (const float*)d_in[5];
  const float* kvb  = (const float*)d_in[6];
  const float* kvA  = (const float*)d_in[7];
  const float* kvB  = (const float*)d_in[8];
  const float* resW = (const float*)d_in[9];
  const float* resw = (const float*)d_in[10];
  float* out = (float*)d_out;
  float* ws  = (float*)d_ws;

  size_t o = 0;
  float* Wc   = ws + o; o += 512*256;
  float* bc   = ws + o; o += 512;
  float* Q    = ws + o; o += (size_t)NTOT*128;
  float* K    = ws + o; o += (size_t)NTOT*128;
  float* V    = ws + o; o += (size_t)NTOT*128;
  float* OP   = ws + o; o += (size_t)BB*MPAD*128;
  float* PM   = ws + o; o += (size_t)BB*MPAD;
  float* PS   = ws + o; o += (size_t)BB*MPAD;
  float* OH   = ws + o; o += (size_t)BB*NH*128;
  float* PACC = ws + o; o += (size_t)BB*NSPLIT*MPAD*128;
  float* PMX  = ws + o; o += (size_t)BB*NSPLIT*MPAD;
  float* PSM  = ws + o; o += (size_t)BB*NSPLIT*MPAD;
  (void)o; (void)ws_size; (void)in_sizes; (void)n_in; (void)out_size;

  k_weights<<<dim3(512), dim3(256), 0, stream>>>(qW,qb,qA,qB,kvW,kvb,kvA,kvB,resW,resw,Wc,bc);
  k_proj<<<dim3((NTOT+63)/64, 8), dim3(256), 0, stream>>>(x, Wc, bc, Q, K, V, out);
  k_attnp<<<dim3(BB, 9, NSPLIT), dim3(256), 0, stream>>>(Q, K, V, PACC, PMX, PSM);
  k_pcombine<<<dim3(BB, MM), dim3(128), 0, stream>>>(PACC, PMX, PSM, OP, PM, PS);
  k_attnh<<<dim3(BB, NH/16), dim3(256), 0, stream>>>(Q, K, V, OP, OH, out);
  k_xp<<<dim3(BB, 9, NSPLIT), dim3(256), 0, stream>>>(Q, K, OH, PM, PS, PACC);
  k_xpreduce<<<dim3(BB, MM), dim3(128), 0, stream>>>(PACC, out);
}

// Round 2
// 4038.872 us; speedup vs baseline: 8.8090x; 8.8090x over previous
//
#include <hip/hip_runtime.h>
#include <hip/hip_bf16.h>
#include <cstddef>

#define MM     281
#define NSEQ   33049
#define BB     4
#define NH     32768          // NSEQ - MM
#define NTOT   (BB*NSEQ)      // 132196
#define MPAD   288
#define NSPLIT 8
#define SCALEQ 0.125f
#define LORAS  2.0f

typedef __attribute__((ext_vector_type(8))) short bf16x8;
typedef __attribute__((ext_vector_type(4))) float f32x4;

static __device__ __forceinline__ short f2bf(float v){
  __hip_bfloat16 h = __float2bfloat16(v);
  return *reinterpret_cast<short*>(&h);
}

// ---------------- K0: fold LoRA + scales into combined weight matrix ----------------
__global__ void k_weights(const float* __restrict__ qW, const float* __restrict__ qb,
                          const float* __restrict__ qA, const float* __restrict__ qB,
                          const float* __restrict__ kvW, const float* __restrict__ kvb,
                          const float* __restrict__ kvA, const float* __restrict__ kvB,
                          const float* __restrict__ resW, const float* __restrict__ resw,
                          float* __restrict__ Wc, float* __restrict__ bc){
  int j = blockIdx.x;     // 0..511
  int c = threadIdx.x;    // 0..255
  float w;
  if (j < 128){
    float l = 0.f;
    #pragma unroll
    for (int r = 0; r < 8; ++r) l += qA[j*8+r]*qB[r*256+c];
    w = SCALEQ*(qW[j*256+c] + LORAS*l);
    if (c==0) bc[j] = SCALEQ*qb[j];
  } else if (j < 384){
    int jj = j-128;
    float l = 0.f;
    #pragma unroll
    for (int r = 0; r < 8; ++r) l += kvA[jj*8+r]*kvB[r*256+c];
    w = kvW[jj*256+c] + LORAS*l;
    if (c==0) bc[j] = kvb[jj];
  } else {
    int jj = j-384;
    w = resw[0]*resW[jj*256+c];
    if (c==0) bc[j] = 0.f;
  }
  Wc[j*256+c] = w;
}

// ---------------- K1: fused projection GEMM  Y = x @ Wc.T + bc ----------------
__global__ __launch_bounds__(256) void k_proj(const float* __restrict__ X,
                       const float* __restrict__ Wc, const float* __restrict__ bc,
                       float* __restrict__ Q, float* __restrict__ K, float* __restrict__ V,
                       float* __restrict__ OUT){
  __shared__ __align__(16) float As[32][68];
  __shared__ __align__(16) float Bs[32][68];
  int tid = threadIdx.x;
  int rowBase = blockIdx.x*64;
  int jBase   = blockIdx.y*64;
  int tm = tid & 15, tn = tid >> 4;
  float acc[4][4];
  #pragma unroll
  for (int i=0;i<4;++i)
    #pragma unroll
    for (int j=0;j<4;++j) acc[i][j]=0.f;

  for (int k0 = 0; k0 < 256; k0 += 32){
    #pragma unroll
    for (int i = 0; i < 8; ++i){
      int lin = tid + 256*i;
      int m = lin >> 5, kk = lin & 31;
      int row = rowBase + m; if (row >= NTOT) row = NTOT-1;
      As[kk][m] = X[(size_t)row*256 + k0 + kk];
      Bs[kk][m] = Wc[(size_t)(jBase+m)*256 + k0 + kk];
    }
    __syncthreads();
    #pragma unroll
    for (int kk = 0; kk < 32; ++kk){
      float4 a = *(const float4*)&As[kk][tm*4];
      float4 b = *(const float4*)&Bs[kk][tn*4];
      acc[0][0]+=a.x*b.x; acc[0][1]+=a.x*b.y; acc[0][2]+=a.x*b.z; acc[0][3]+=a.x*b.w;
      acc[1][0]+=a.y*b.x; acc[1][1]+=a.y*b.y; acc[1][2]+=a.y*b.z; acc[1][3]+=a.y*b.w;
      acc[2][0]+=a.z*b.x; acc[2][1]+=a.z*b.y; acc[2][2]+=a.z*b.z; acc[2][3]+=a.z*b.w;
      acc[3][0]+=a.w*b.x; acc[3][1]+=a.w*b.y; acc[3][2]+=a.w*b.z; acc[3][3]+=a.w*b.w;
    }
    __syncthreads();
  }
  #pragma unroll
  for (int i=0;i<4;++i){
    int row = rowBase + tm*4 + i;
    if (row >= NTOT) continue;
    #pragma unroll
    for (int j=0;j<4;++j){
      int jj = jBase + tn*4 + j;
      float v = acc[i][j] + bc[jj];
      size_t o = (size_t)row*128;
      if      (jj < 128) Q[o + jj]       = v;
      else if (jj < 256) K[o + jj-128]   = v;
      else if (jj < 384) V[o + jj-256]   = v;
      else               OUT[o + jj-384] = v;
    }
  }
}

// ---------------- K1b: convert Q_h to bf16 ----------------
__global__ void k_cvtq(const float* __restrict__ Q, __hip_bfloat16* __restrict__ Qhb){
  size_t idx = (size_t)blockIdx.x*256 + threadIdx.x;
  if (idx >= (size_t)BB*NH*32) return;
  size_t e = idx*4;
  int b = (int)(e >> 22);            // NH*128 = 2^22
  size_t r = e & 4194303ul;
  float4 v = *(const float4*)&Q[((size_t)b*NSEQ + MM)*128 + r];
  short4 o;
  o.x = f2bf(v.x); o.y = f2bf(v.y); o.z = f2bf(v.z); o.w = f2bf(v.w);
  *(short4*)&Qhb[e] = o;
}

// ---------------- K1c: bf16 K_p (row-major, padded) + V_p^T (d-major, padded) --------
__global__ void k_prep(const float* __restrict__ K, const float* __restrict__ V,
                       __hip_bfloat16* __restrict__ Kpb, __hip_bfloat16* __restrict__ VTb,
                       __hip_bfloat16* __restrict__ OPTb){
  int b = blockIdx.x, m = blockIdx.y, d = threadIdx.x;  // m<288, d<128
  float kv = (m < MM) ? K[((size_t)b*NSEQ + m)*128 + d] : 0.f;
  float vv = (m < MM) ? V[((size_t)b*NSEQ + m)*128 + d] : 0.f;
  short* kp = (short*)Kpb; short* vt = (short*)VTb; short* ot = (short*)OPTb;
  kp[((size_t)b*MPAD + m)*128 + d] = f2bf(kv);
  vt[((size_t)b*128 + d)*MPAD + m] = f2bf(vv);
  if (m >= MM) ot[((size_t)b*128 + d)*MPAD + m] = f2bf(0.f);
}

// ---------------- K2: flash attn_p partials (out_p accumulation, split over keys) ------
__global__ __launch_bounds__(256) void k_attnp(const float* __restrict__ Q,
                        const float* __restrict__ K, const float* __restrict__ V,
                        float* __restrict__ PACC, float* __restrict__ PMX,
                        float* __restrict__ PSM){
  __shared__ float qs[32][129];
  __shared__ float ks[64][129];
  __shared__ float vs[64][129];
  __shared__ float Ssh[32][65];
  int b = blockIdx.x, mt = blockIdx.y, s = blockIdx.z;
  int tid = threadIdx.x;
  int r = tid & 31, g = tid >> 5;   // r: m-row, g: d-slice of 16
  int m0 = mt*32;
  for (int i = tid; i < 32*128; i += 256){
    int rr = i >> 7, d = i & 127;
    int m = m0 + rr;
    qs[rr][d] = (m < MM) ? Q[((size_t)b*NSEQ + m)*128 + d] : 0.f;
  }
  __syncthreads();
  float acc[16];
  #pragma unroll
  for (int i=0;i<16;++i) acc[i]=0.f;
  float rmax = -1e30f, rsum = 0.f;
  int nnBase = s*(NH/NSPLIT);
  for (int c = 0; c < (NH/NSPLIT)/64; ++c){
    int nn0 = nnBase + c*64;
    for (int i = tid; i < 64*128; i += 256){
      int rr = i >> 7, d = i & 127;
      size_t gr = ((size_t)b*NSEQ + MM + nn0 + rr)*128 + d;
      ks[rr][d] = K[gr];
      vs[rr][d] = V[gr];
    }
    __syncthreads();
    float sc[8];
    #pragma unroll
    for (int i=0;i<8;++i) sc[i]=0.f;
    for (int d=0; d<128; ++d){
      float qd = qs[r][d];
      #pragma unroll
      for (int i=0;i<8;++i) sc[i] += qd*ks[g*8+i][d];
    }
    #pragma unroll
    for (int i=0;i<8;++i) Ssh[r][g*8+i] = sc[i];
    __syncthreads();
    float cmax = -1e30f;
    #pragma unroll
    for (int nn=0;nn<64;++nn) cmax = fmaxf(cmax, Ssh[r][nn]);
    float mnew = fmaxf(rmax, cmax);
    float scale = __expf(rmax - mnew);
    rsum *= scale;
    #pragma unroll
    for (int i=0;i<16;++i) acc[i] *= scale;
    for (int nn=0;nn<64;++nn){
      float w = __expf(Ssh[r][nn]-mnew);
      rsum += w;
      const float* vr = &vs[nn][g*16];
      #pragma unroll
      for (int i=0;i<16;++i) acc[i] += w*vr[i];
    }
    rmax = mnew;
    __syncthreads();
  }
  int m = m0 + r;
  size_t pb = (((size_t)b*NSPLIT + s)*MPAD + m);
  #pragma unroll
  for (int i=0;i<16;++i) PACC[pb*128 + g*16 + i] = acc[i];
  if (g == 0){ PMX[pb] = rmax; PSM[pb] = rsum; }
}

// ---------------- K3: combine attn_p splits -> out_p + final stats (+bf16 OP^T) -------
__global__ void k_pcombine(const float* __restrict__ PACC, const float* __restrict__ PMX,
                           const float* __restrict__ PSM,
                           float* __restrict__ OP, float* __restrict__ PM,
                           float* __restrict__ PS, __hip_bfloat16* __restrict__ OPTb){
  int b = blockIdx.x, m = blockIdx.y;   // m < 281
  int d = threadIdx.x;                  // 0..127
  float M = -1e30f;
  #pragma unroll
  for (int s=0;s<NSPLIT;++s) M = fmaxf(M, PMX[((size_t)b*NSPLIT+s)*MPAD+m]);
  float sum = 0.f, a = 0.f;
  #pragma unroll
  for (int s=0;s<NSPLIT;++s){
    size_t pb = ((size_t)b*NSPLIT+s)*MPAD+m;
    float e = __expf(PMX[pb]-M);
    sum += PSM[pb]*e;
    a   += PACC[pb*128+d]*e;
  }
  float val = a/sum;
  OP[((size_t)b*MPAD+m)*128+d] = val;
  ((short*)OPTb)[((size_t)b*128+d)*MPAD+m] = f2bf(val);
  if (d==0){ PM[(size_t)b*MPAD+m]=M; PS[(size_t)b*MPAD+m]=sum; }
}

// ---------------- K4: attn_h via MFMA: S=Q·Kp^T -> reg softmax -> out_h & xh ----------
__global__ __launch_bounds__(256) void k_attnh2(const __hip_bfloat16* __restrict__ Qhb,
                        const __hip_bfloat16* __restrict__ Kpb,
                        const __hip_bfloat16* __restrict__ VTb,
                        const __hip_bfloat16* __restrict__ OPTb,
                        float* __restrict__ OH, float* __restrict__ OUT){
  __shared__ short P_lds[4][16][296];
  int tid = threadIdx.x;
  int wid = tid >> 6, lane = tid & 63;
  int lo = lane & 15, hi = lane >> 4;
  int b = blockIdx.x;
  int q0 = blockIdx.y*64 + wid*16;   // q row within h-block [0,NH)

  const short* Qp  = (const short*)Qhb;
  const short* Kp  = (const short*)Kpb;
  const short* VT  = (const short*)VTb;
  const short* OPT = (const short*)OPTb;

  // A fragments of Q tile: row = lo, k = ks*32 + hi*8 .. +8
  bf16x8 aq[4];
  size_t qrow = ((size_t)b*NH + q0 + lo)*128;
  #pragma unroll
  for (int ks=0;ks<4;++ks) aq[ks] = *(const bf16x8*)(Qp + qrow + ks*32 + hi*8);

  // S = Q @ Kp^T : 18 n-tiles of 16 keys
  f32x4 s[18];
  #pragma unroll
  for (int nt=0;nt<18;++nt){
    f32x4 acc = {0.f,0.f,0.f,0.f};
    size_t krow = ((size_t)b*MPAD + nt*16 + lo)*128;
    #pragma unroll
    for (int ks=0;ks<4;++ks){
      bf16x8 bk = *(const bf16x8*)(Kp + krow + ks*32 + hi*8);
      acc = __builtin_amdgcn_mfma_f32_16x16x32_bf16(aq[ks], bk, acc, 0,0,0);
    }
    s[nt] = acc;
  }
  // mask invalid keys (cols 281..287 live in nt=17, lo>=9)
  if (lo >= 9){
    s[17][0] = -1e30f; s[17][1] = -1e30f; s[17][2] = -1e30f; s[17][3] = -1e30f;
  }
  // register softmax: row r = hi*4 + i; its 16 cols/tile sit across the 16-lane group
  #pragma unroll
  for (int i=0;i<4;++i){
    float m = -1e30f;
    #pragma unroll
    for (int nt=0;nt<18;++nt) m = fmaxf(m, s[nt][i]);
    #pragma unroll
    for (int d=1; d<16; d<<=1) m = fmaxf(m, __shfl_xor(m, d));
    float ss = 0.f;
    #pragma unroll
    for (int nt=0;nt<18;++nt){ float w = __expf(s[nt][i]-m); s[nt][i] = w; ss += w; }
    #pragma unroll
    for (int d=1; d<16; d<<=1) ss += __shfl_xor(ss, d);
    float rinv = 1.f/ss;
    int r = hi*4 + i;
    #pragma unroll
    for (int nt=0;nt<18;++nt) P_lds[wid][r][nt*16+lo] = f2bf(s[nt][i]*rinv);
  }
  // P A-fragments (wave-private LDS region; same-wave RAW -> no barrier needed)
  bf16x8 pa[9];
  #pragma unroll
  for (int ks=0;ks<9;++ks) pa[ks] = *(const bf16x8*)&P_lds[wid][lo][ks*32 + hi*8];

  // out_h = P @ V_p ; xh = P @ out_p   (B-fragments from transposed bf16, L2-resident)
  #pragma unroll
  for (int nt=0; nt<8; ++nt){
    f32x4 aoh = {0.f,0.f,0.f,0.f};
    f32x4 axh = {0.f,0.f,0.f,0.f};
    size_t vrow = ((size_t)b*128 + nt*16 + lo)*MPAD;
    #pragma unroll
    for (int ks=0;ks<9;++ks){
      bf16x8 bv = *(const bf16x8*)(VT + vrow + ks*32 + hi*8);
      aoh = __builtin_amdgcn_mfma_f32_16x16x32_bf16(pa[ks], bv, aoh, 0,0,0);
      bf16x8 bo = *(const bf16x8*)(OPT + vrow + ks*32 + hi*8);
      axh = __builtin_amdgcn_mfma_f32_16x16x32_bf16(pa[ks], bo, axh, 0,0,0);
    }
    #pragma unroll
    for (int i=0;i<4;++i){
      size_t rq = (size_t)q0 + hi*4 + i;
      int d = nt*16 + lo;
      OH[((size_t)b*NH + rq)*128 + d] = aoh[i];
      size_t oo = ((size_t)b*NSEQ + MM + rq)*128 + d;
      OUT[oo] += axh[i];
    }
  }
}

// ---------------- K5: xp = attn_p @ out_h (recompute weights from stats), partials ------
__global__ __launch_bounds__(256) void k_xp(const float* __restrict__ Q,
                     const float* __restrict__ K, const float* __restrict__ OH,
                     const float* __restrict__ PM, const float* __restrict__ PS,
                     float* __restrict__ PACC){
  __shared__ float qs[32][129];
  __shared__ float ks[64][129];
  __shared__ float os[64][129];
  __shared__ float Ssh[32][65];
  int b = blockIdx.x, mt = blockIdx.y, s = blockIdx.z;
  int tid = threadIdx.x;
  int r = tid & 31, g = tid >> 5;
  int m0 = mt*32;
  for (int i = tid; i < 32*128; i += 256){
    int rr = i >> 7, d = i & 127;
    int m = m0 + rr;
    qs[rr][d] = (m < MM) ? Q[((size_t)b*NSEQ + m)*128 + d] : 0.f;
  }
  __syncthreads();
  int m = m0 + r;
  float pmax = (m < MM) ? PM[(size_t)b*MPAD+m] : 0.f;
  float rinv = (m < MM) ? 1.f/PS[(size_t)b*MPAD+m] : 0.f;
  float acc[16];
  #pragma unroll
  for (int i=0;i<16;++i) acc[i]=0.f;
  int nnBase = s*(NH/NSPLIT);
  for (int c = 0; c < (NH/NSPLIT)/64; ++c){
    int nn0 = nnBase + c*64;
    for (int i = tid; i < 64*128; i += 256){
      int rr = i >> 7, d = i & 127;
      ks[rr][d] = K [((size_t)b*NSEQ + MM + nn0 + rr)*128 + d];
      os[rr][d] = OH[((size_t)b*NH  +      nn0 + rr)*128 + d];
    }
    __syncthreads();
    float sc[8];
    #pragma unroll
    for (int i=0;i<8;++i) sc[i]=0.f;
    for (int d=0; d<128; ++d){
      float qd = qs[r][d];
      #pragma unroll
      for (int i=0;i<8;++i) sc[i] += qd*ks[g*8+i][d];
    }
    #pragma unroll
    for (int i=0;i<8;++i) Ssh[r][g*8+i] = sc[i];
    __syncthreads();
    for (int nn=0;nn<64;++nn){
      float w = __expf(Ssh[r][nn]-pmax);
      const float* orow = &os[nn][g*16];
      #pragma unroll
      for (int i=0;i<16;++i) acc[i] += w*orow[i];
    }
    __syncthreads();
  }
  size_t pb = (((size_t)b*NSPLIT + s)*MPAD + m);
  #pragma unroll
  for (int i=0;i<16;++i) PACC[pb*128 + g*16 + i] = acc[i]*rinv;
}

// ---------------- K6: deterministic reduction of xp partials into d_out ----------------
__global__ void k_xpreduce(const float* __restrict__ PACC, float* __restrict__ OUT){
  int b = blockIdx.x, m = blockIdx.y;   // m < 281
  int d = threadIdx.x;
  float a = 0.f;
  #pragma unroll
  for (int s=0;s<NSPLIT;++s) a += PACC[(((size_t)b*NSPLIT+s)*MPAD+m)*128+d];
  OUT[((size_t)b*NSEQ+m)*128+d] += a;
}

extern "C" void kernel_launch(void* const* d_in, const int* in_sizes, int n_in,
                              void* d_out, int out_size, void* d_ws, size_t ws_size,
                              hipStream_t stream){
  const float* x    = (const float*)d_in[0];
  const float* qW   = (const float*)d_in[1];
  const float* qb   = (const float*)d_in[2];
  const float* qA   = (const float*)d_in[3];
  const float* qB   = (const float*)d_in[4];
  const float* kvW  = (const float*)d_in[5];
  const float* kvb  = (const float*)d_in[6];
  const float* kvA  = (const float*)d_in[7];
  const float* kvB  = (const float*)d_in[8];
  const float* resW = (const float*)d_in[9];
  const float* resw = (const float*)d_in[10];
  float* out = (float*)d_out;

  char* base = (char*)d_ws;
  size_t off = 0;
  auto alloc = [&](size_t bytes) -> void* {
    void* p = base + off; off += (bytes + 255) & ~(size_t)255; return p;
  };
  float* Wc   = (float*)alloc(512*256*4);
  float* bc   = (float*)alloc(512*4);
  float* Q    = (float*)alloc((size_t)NTOT*128*4);
  float* K    = (float*)alloc((size_t)NTOT*128*4);
  float* V    = (float*)alloc((size_t)NTOT*128*4);
  float* OP   = (float*)alloc((size_t)BB*MPAD*128*4);
  float* PM   = (float*)alloc((size_t)BB*MPAD*4);
  float* PS   = (float*)alloc((size_t)BB*MPAD*4);
  float* OH   = (float*)alloc((size_t)BB*NH*128*4);
  float* PACC = (float*)alloc((size_t)BB*NSPLIT*MPAD*128*4);
  float* PMX  = (float*)alloc((size_t)BB*NSPLIT*MPAD*4);
  float* PSM  = (float*)alloc((size_t)BB*NSPLIT*MPAD*4);
  __hip_bfloat16* Qhb  = (__hip_bfloat16*)alloc((size_t)BB*NH*128*2);
  __hip_bfloat16* Kpb  = (__hip_bfloat16*)alloc((size_t)BB*MPAD*128*2);
  __hip_bfloat16* VTb  = (__hip_bfloat16*)alloc((size_t)BB*128*MPAD*2);
  __hip_bfloat16* OPTb = (__hip_bfloat16*)alloc((size_t)BB*128*MPAD*2);
  (void)off; (void)ws_size; (void)in_sizes; (void)n_in; (void)out_size;

  k_weights<<<dim3(512), dim3(256), 0, stream>>>(qW,qb,qA,qB,kvW,kvb,kvA,kvB,resW,resw,Wc,bc);
  k_proj<<<dim3((NTOT+63)/64, 8), dim3(256), 0, stream>>>(x, Wc, bc, Q, K, V, out);
  k_cvtq<<<dim3((BB*NH*32+255)/256), dim3(256), 0, stream>>>(Q, Qhb);
  k_prep<<<dim3(BB, MPAD), dim3(128), 0, stream>>>(K, V, Kpb, VTb, OPTb);
  k_attnp<<<dim3(BB, 9, NSPLIT), dim3(256), 0, stream>>>(Q, K, V, PACC, PMX, PSM);
  k_pcombine<<<dim3(BB, MM), dim3(128), 0, stream>>>(PACC, PMX, PSM, OP, PM, PS, OPTb);
  k_attnh2<<<dim3(BB, NH/64), dim3(256), 0, stream>>>(Qhb, Kpb, VTb, OPTb, OH, out);
  k_xp<<<dim3(BB, 9, NSPLIT), dim3(256), 0, stream>>>(Q, K, OH, PM, PS, PACC);
  k_xpreduce<<<dim3(BB, MM), dim3(128), 0, stream>>>(PACC, out);
}

// Round 3
// 1095.203 us; speedup vs baseline: 32.4857x; 3.6878x over previous
//
#include <hip/hip_runtime.h>
#include <hip/hip_bf16.h>
#include <cstddef>

#define MM     281
#define NSEQ   33049
#define BB     4
#define NH     32768          // NSEQ - MM
#define NTOT   (BB*NSEQ)      // 132196
#define MPAD   288
#define NSP    32             // key splits for p-attention
#define SCALEQ 0.125f
#define LORAS  2.0f

typedef __attribute__((ext_vector_type(8))) short bf16x8;
typedef __attribute__((ext_vector_type(4))) float f32x4;

static __device__ __forceinline__ short f2bf(float v){
  __hip_bfloat16 h = __float2bfloat16(v);
  return *reinterpret_cast<short*>(&h);
}

// ---------------- K0: fold LoRA + scales into combined weight matrix ----------------
__global__ void k_weights(const float* __restrict__ qW, const float* __restrict__ qb,
                          const float* __restrict__ qA, const float* __restrict__ qB,
                          const float* __restrict__ kvW, const float* __restrict__ kvb,
                          const float* __restrict__ kvA, const float* __restrict__ kvB,
                          const float* __restrict__ resW, const float* __restrict__ resw,
                          float* __restrict__ Wc, float* __restrict__ bc){
  int j = blockIdx.x;     // 0..511
  int c = threadIdx.x;    // 0..255
  float w;
  if (j < 128){
    float l = 0.f;
    #pragma unroll
    for (int r = 0; r < 8; ++r) l += qA[j*8+r]*qB[r*256+c];
    w = SCALEQ*(qW[j*256+c] + LORAS*l);
    if (c==0) bc[j] = SCALEQ*qb[j];
  } else if (j < 384){
    int jj = j-128;
    float l = 0.f;
    #pragma unroll
    for (int r = 0; r < 8; ++r) l += kvA[jj*8+r]*kvB[r*256+c];
    w = kvW[jj*256+c] + LORAS*l;
    if (c==0) bc[j] = kvb[jj];
  } else {
    int jj = j-384;
    w = resw[0]*resW[jj*256+c];
    if (c==0) bc[j] = 0.f;
  }
  Wc[j*256+c] = w;
}

// ---------------- K1: fused projection GEMM  Y = x @ Wc.T + bc ----------------
// Q,K written directly as bf16 row-major; V f32; res rows -> d_out f32.
__global__ __launch_bounds__(256) void k_proj(const float* __restrict__ X,
                       const float* __restrict__ Wc, const float* __restrict__ bc,
                       short* __restrict__ QB, short* __restrict__ KB,
                       float* __restrict__ V, float* __restrict__ OUT){
  __shared__ __align__(16) float As[32][68];
  __shared__ __align__(16) float Bs[32][68];
  int tid = threadIdx.x;
  int rowBase = blockIdx.x*64;
  int jBase   = blockIdx.y*64;
  int tm = tid & 15, tn = tid >> 4;
  float acc[4][4];
  #pragma unroll
  for (int i=0;i<4;++i)
    #pragma unroll
    for (int j=0;j<4;++j) acc[i][j]=0.f;

  for (int k0 = 0; k0 < 256; k0 += 32){
    #pragma unroll
    for (int i = 0; i < 8; ++i){
      int lin = tid + 256*i;
      int m = lin >> 5, kk = lin & 31;
      int row = rowBase + m; if (row >= NTOT) row = NTOT-1;
      As[kk][m] = X[(size_t)row*256 + k0 + kk];
      Bs[kk][m] = Wc[(size_t)(jBase+m)*256 + k0 + kk];
    }
    __syncthreads();
    #pragma unroll
    for (int kk = 0; kk < 32; ++kk){
      float4 a = *(const float4*)&As[kk][tm*4];
      float4 b = *(const float4*)&Bs[kk][tn*4];
      acc[0][0]+=a.x*b.x; acc[0][1]+=a.x*b.y; acc[0][2]+=a.x*b.z; acc[0][3]+=a.x*b.w;
      acc[1][0]+=a.y*b.x; acc[1][1]+=a.y*b.y; acc[1][2]+=a.y*b.z; acc[1][3]+=a.y*b.w;
      acc[2][0]+=a.z*b.x; acc[2][1]+=a.z*b.y; acc[2][2]+=a.z*b.z; acc[2][3]+=a.z*b.w;
      acc[3][0]+=a.w*b.x; acc[3][1]+=a.w*b.y; acc[3][2]+=a.w*b.z; acc[3][3]+=a.w*b.w;
    }
    __syncthreads();
  }
  int jj0 = jBase + tn*4;
  float b0 = bc[jj0], b1 = bc[jj0+1], b2 = bc[jj0+2], b3 = bc[jj0+3];
  #pragma unroll
  for (int i=0;i<4;++i){
    int row = rowBase + tm*4 + i;
    if (row >= NTOT) continue;
    float v0 = acc[i][0]+b0, v1 = acc[i][1]+b1, v2 = acc[i][2]+b2, v3 = acc[i][3]+b3;
    if (jj0 < 128){
      short4 o; o.x=f2bf(v0); o.y=f2bf(v1); o.z=f2bf(v2); o.w=f2bf(v3);
      *(short4*)&QB[(size_t)row*128 + jj0] = o;
    } else if (jj0 < 256){
      short4 o; o.x=f2bf(v0); o.y=f2bf(v1); o.z=f2bf(v2); o.w=f2bf(v3);
      *(short4*)&KB[(size_t)row*128 + jj0-128] = o;
    } else if (jj0 < 384){
      float4 o; o.x=v0; o.y=v1; o.z=v2; o.w=v3;
      *(float4*)&V[(size_t)row*128 + jj0-256] = o;
    } else {
      float4 o; o.x=v0; o.y=v1; o.z=v2; o.w=v3;
      *(float4*)&OUT[(size_t)row*128 + jj0-384] = o;
    }
  }
}

// ---------------- K1b: V_p^T bf16 (padded) + zero-pad of OP^T tail ----------------
__global__ void k_prep(const float* __restrict__ V, short* __restrict__ VTb,
                       short* __restrict__ OPTb){
  int b = blockIdx.x, m = blockIdx.y, d = threadIdx.x;  // m<288, d<128
  float vv = (m < MM) ? V[((size_t)b*NSEQ + m)*128 + d] : 0.f;
  VTb[((size_t)b*128 + d)*MPAD + m] = f2bf(vv);
  if (m >= MM) OPTb[((size_t)b*128 + d)*MPAD + m] = 0;
}

// ---------------- K1c: transpose V_h (f32) -> VhT bf16 [b][128][NH] ----------------
__global__ __launch_bounds__(256) void k_transV(const float* __restrict__ V,
                                                short* __restrict__ VhT){
  __shared__ float t[64][65];
  int b = blockIdx.x, k0 = blockIdx.y*64, d0 = blockIdx.z*64;
  int tid = threadIdx.x;
  #pragma unroll
  for (int i=0;i<16;++i){
    int idx = tid + 256*i; int r = idx>>6, c = idx&63;
    t[r][c] = V[((size_t)b*NSEQ + MM + k0 + r)*128 + d0 + c];
  }
  __syncthreads();
  #pragma unroll
  for (int i=0;i<16;++i){
    int idx = tid + 256*i; int r = idx>>6, c = idx&63;  // r: d, c: key
    VhT[((size_t)b*128 + d0 + r)*NH + k0 + c] = f2bf(t[c][r]);
  }
}

// ---------------- K1d: transpose OHB bf16 -> OHT bf16 [b][128][NH] ----------------
__global__ __launch_bounds__(256) void k_transOH(const short* __restrict__ OHB,
                                                 short* __restrict__ OHT){
  __shared__ short t[64][74];
  int b = blockIdx.x, k0 = blockIdx.y*64, d0 = blockIdx.z*64;
  int tid = threadIdx.x;
  #pragma unroll
  for (int i=0;i<16;++i){
    int idx = tid + 256*i; int r = idx>>6, c = idx&63;
    t[r][c] = OHB[((size_t)b*NH + k0 + r)*128 + d0 + c];
  }
  __syncthreads();
  #pragma unroll
  for (int i=0;i<16;++i){
    int idx = tid + 256*i; int r = idx>>6, c = idx&63;  // r: d, c: key
    OHT[((size_t)b*128 + d0 + r)*NH + k0 + c] = t[c][r];
  }
}

// ---------------- K2: MFMA flash attn_p partials (split over keys) ----------------
// 1 wave per block; wave owns 16 q-rows (m-tile), iterates 1024 keys of its split.
__global__ __launch_bounds__(64) void k_attnp2(const short* __restrict__ QB,
                        const short* __restrict__ KB, const short* __restrict__ VhT,
                        float* __restrict__ PACC, float* __restrict__ PMX,
                        float* __restrict__ PSM){
  __shared__ short P_lds[16][40];
  int lane = threadIdx.x;
  int lo = lane & 15, hi = lane >> 4;
  int mt = blockIdx.x;   // 0..17
  int s  = blockIdx.y;   // 0..NSP-1
  int b  = blockIdx.z;

  bf16x8 aq[4];
  int qrow = mt*16 + lo;
  if (qrow < MM){
    size_t qb = ((size_t)b*NSEQ + qrow)*128;
    #pragma unroll
    for (int ks=0;ks<4;++ks) aq[ks] = *(const bf16x8*)(QB + qb + ks*32 + hi*8);
  } else {
    #pragma unroll
    for (int ks=0;ks<4;++ks) aq[ks] = bf16x8{0,0,0,0,0,0,0,0};
  }

  float rmax[4], rsum[4];
  #pragma unroll
  for (int i=0;i<4;++i){ rmax[i] = -1e30f; rsum[i] = 0.f; }
  f32x4 acc[8];
  #pragma unroll
  for (int nt=0;nt<8;++nt) acc[nt] = f32x4{0.f,0.f,0.f,0.f};

  const int key0 = s*(NH/NSP);            // 1024 keys per split
  const size_t kbase = ((size_t)b*NSEQ + MM)*128;
  const size_t vbase = (size_t)b*128*NH;

  bf16x8 fr[2][16];   // [0..7]=K frags (2 tiles x 4 ksteps), [8..15]=V frags (8 d-tiles)
  auto loadFr = [&](int kk, bf16x8* dst){
    #pragma unroll
    for (int t=0;t<2;++t)
      #pragma unroll
      for (int ks=0;ks<4;++ks)
        dst[t*4+ks] = *(const bf16x8*)(KB + kbase + (size_t)(kk + t*16 + lo)*128 + ks*32 + hi*8);
    #pragma unroll
    for (int nt=0;nt<8;++nt)
      dst[8+nt] = *(const bf16x8*)(VhT + vbase + (size_t)(nt*16 + lo)*NH + kk + hi*8);
  };

  auto body = [&](bf16x8* cur, bf16x8* nxt, int c, bool pre){
    if (pre) loadFr(key0 + (c+1)*32, nxt);
    f32x4 s0 = {0.f,0.f,0.f,0.f}, s1 = {0.f,0.f,0.f,0.f};
    #pragma unroll
    for (int ks=0;ks<4;++ks){
      s0 = __builtin_amdgcn_mfma_f32_16x16x32_bf16(aq[ks], cur[ks],   s0, 0,0,0);
      s1 = __builtin_amdgcn_mfma_f32_16x16x32_bf16(aq[ks], cur[4+ks], s1, 0,0,0);
    }
    #pragma unroll
    for (int i=0;i<4;++i){
      float mc = fmaxf(s0[i], s1[i]);
      #pragma unroll
      for (int d=1; d<16; d<<=1) mc = fmaxf(mc, __shfl_xor(mc, d));
      float mnew = fmaxf(rmax[i], mc);
      float scale = __expf(rmax[i]-mnew);
      float p0 = __expf(s0[i]-mnew), p1 = __expf(s1[i]-mnew);
      rsum[i] = rsum[i]*scale + p0 + p1;
      rmax[i] = mnew;
      #pragma unroll
      for (int nt=0;nt<8;++nt) acc[nt][i] *= scale;
      P_lds[hi*4+i][lo]    = f2bf(p0);
      P_lds[hi*4+i][lo+16] = f2bf(p1);
    }
    bf16x8 pa = *(const bf16x8*)&P_lds[lo][hi*8];
    #pragma unroll
    for (int nt=0;nt<8;++nt)
      acc[nt] = __builtin_amdgcn_mfma_f32_16x16x32_bf16(pa, cur[8+nt], acc[nt], 0,0,0);
  };

  loadFr(key0, fr[0]);
  for (int c = 0; c < (NH/NSP)/32; c += 2){
    body(fr[0], fr[1], c,   true);
    body(fr[1], fr[0], c+1, c+2 < (NH/NSP)/32);
  }

  // epilogue: reduce lane-partial rowsums, write partials + stats
  #pragma unroll
  for (int i=0;i<4;++i){
    #pragma unroll
    for (int d=1; d<16; d<<=1) rsum[i] += __shfl_xor(rsum[i], d);
  }
  size_t pb = ((size_t)(b*NSP + s)*MPAD + mt*16);
  #pragma unroll
  for (int nt=0;nt<8;++nt)
    #pragma unroll
    for (int i=0;i<4;++i)
      PACC[(pb + hi*4 + i)*128 + nt*16 + lo] = acc[nt][i];
  if (lo == 0){
    #pragma unroll
    for (int i=0;i<4;++i){
      PMX[pb + hi*4 + i] = rmax[i];
      PSM[pb + hi*4 + i] = rsum[i];
    }
  }
}

// ---------------- K3: combine attn_p splits -> OP^T bf16 + final stats ----------------
__global__ void k_pcombine(const float* __restrict__ PACC, const float* __restrict__ PMX,
                           const float* __restrict__ PSM,
                           float* __restrict__ PM, float* __restrict__ PS,
                           short* __restrict__ OPTb){
  int b = blockIdx.x, m = blockIdx.y;   // m < 281
  int d = threadIdx.x;                  // 0..127
  float M = -1e30f;
  #pragma unroll
  for (int s=0;s<NSP;++s) M = fmaxf(M, PMX[((size_t)b*NSP+s)*MPAD+m]);
  float sum = 0.f, a = 0.f;
  #pragma unroll
  for (int s=0;s<NSP;++s){
    size_t pb = ((size_t)b*NSP+s)*MPAD+m;
    float e = __expf(PMX[pb]-M);
    sum += PSM[pb]*e;
    a   += PACC[pb*128+d]*e;
  }
  OPTb[((size_t)b*128+d)*MPAD+m] = f2bf(a/sum);
  if (d==0){ PM[(size_t)b*MPAD+m]=M; PS[(size_t)b*MPAD+m]=sum; }
}

// ---------------- K4: attn_h via MFMA: S=Q·Kp^T -> reg softmax -> out_h & xh ----------
__global__ __launch_bounds__(256) void k_attnh2(const short* __restrict__ QB,
                        const short* __restrict__ KB,
                        const short* __restrict__ VTb,
                        const short* __restrict__ OPTb,
                        short* __restrict__ OHB, float* __restrict__ OUT){
  __shared__ short P_lds[4][16][296];
  int tid = threadIdx.x;
  int wid = tid >> 6, lane = tid & 63;
  int lo = lane & 15, hi = lane >> 4;
  int b = blockIdx.x;
  int q0 = blockIdx.y*64 + wid*16;   // q row within h-block [0,NH)

  bf16x8 aq[4];
  size_t qrow = ((size_t)b*NSEQ + MM + q0 + lo)*128;
  #pragma unroll
  for (int ks=0;ks<4;++ks) aq[ks] = *(const bf16x8*)(QB + qrow + ks*32 + hi*8);

  // S = Q @ Kp^T : 18 n-tiles of 16 keys
  f32x4 s[18];
  #pragma unroll
  for (int nt=0;nt<18;++nt){
    f32x4 acc = {0.f,0.f,0.f,0.f};
    size_t krow = ((size_t)b*NSEQ + nt*16 + lo)*128;
    #pragma unroll
    for (int ks=0;ks<4;++ks){
      bf16x8 bk = *(const bf16x8*)(KB + krow + ks*32 + hi*8);
      acc = __builtin_amdgcn_mfma_f32_16x16x32_bf16(aq[ks], bk, acc, 0,0,0);
    }
    s[nt] = acc;
  }
  // mask invalid keys (cols 281..287 live in nt=17, lo>=9)
  if (lo >= 9){
    s[17][0] = -1e30f; s[17][1] = -1e30f; s[17][2] = -1e30f; s[17][3] = -1e30f;
  }
  #pragma unroll
  for (int i=0;i<4;++i){
    float m = -1e30f;
    #pragma unroll
    for (int nt=0;nt<18;++nt) m = fmaxf(m, s[nt][i]);
    #pragma unroll
    for (int d=1; d<16; d<<=1) m = fmaxf(m, __shfl_xor(m, d));
    float ss = 0.f;
    #pragma unroll
    for (int nt=0;nt<18;++nt){ float w = __expf(s[nt][i]-m); s[nt][i] = w; ss += w; }
    #pragma unroll
    for (int d=1; d<16; d<<=1) ss += __shfl_xor(ss, d);
    float rinv = 1.f/ss;
    int r = hi*4 + i;
    #pragma unroll
    for (int nt=0;nt<18;++nt) P_lds[wid][r][nt*16+lo] = f2bf(s[nt][i]*rinv);
  }
  bf16x8 pa[9];
  #pragma unroll
  for (int ks=0;ks<9;++ks) pa[ks] = *(const bf16x8*)&P_lds[wid][lo][ks*32 + hi*8];

  #pragma unroll
  for (int nt=0; nt<8; ++nt){
    f32x4 aoh = {0.f,0.f,0.f,0.f};
    f32x4 axh = {0.f,0.f,0.f,0.f};
    size_t vrow = ((size_t)b*128 + nt*16 + lo)*MPAD;
    #pragma unroll
    for (int ks=0;ks<9;++ks){
      bf16x8 bv = *(const bf16x8*)(VTb + vrow + ks*32 + hi*8);
      aoh = __builtin_amdgcn_mfma_f32_16x16x32_bf16(pa[ks], bv, aoh, 0,0,0);
      bf16x8 bo = *(const bf16x8*)(OPTb + vrow + ks*32 + hi*8);
      axh = __builtin_amdgcn_mfma_f32_16x16x32_bf16(pa[ks], bo, axh, 0,0,0);
    }
    #pragma unroll
    for (int i=0;i<4;++i){
      size_t rq = (size_t)q0 + hi*4 + i;
      int d = nt*16 + lo;
      OHB[((size_t)b*NH + rq)*128 + d] = f2bf(aoh[i]);
      size_t oo = ((size_t)b*NSEQ + MM + rq)*128 + d;
      OUT[oo] += axh[i];
    }
  }
}

// ---------------- K5: xp partials = attn_p @ out_h via MFMA (recomputed weights) -------
__global__ __launch_bounds__(64) void k_xp2(const short* __restrict__ QB,
                     const short* __restrict__ KB, const short* __restrict__ OHT,
                     const float* __restrict__ PM, const float* __restrict__ PS,
                     float* __restrict__ PACC){
  __shared__ short P_lds[16][40];
  int lane = threadIdx.x;
  int lo = lane & 15, hi = lane >> 4;
  int mt = blockIdx.x;   // 0..17
  int s  = blockIdx.y;   // 0..NSP-1
  int b  = blockIdx.z;

  bf16x8 aq[4];
  int qrow = mt*16 + lo;
  if (qrow < MM){
    size_t qb = ((size_t)b*NSEQ + qrow)*128;
    #pragma unroll
    for (int ks=0;ks<4;++ks) aq[ks] = *(const bf16x8*)(QB + qb + ks*32 + hi*8);
  } else {
    #pragma unroll
    for (int ks=0;ks<4;++ks) aq[ks] = bf16x8{0,0,0,0,0,0,0,0};
  }

  float M[4], rinv[4];
  #pragma unroll
  for (int i=0;i<4;++i){
    int row = mt*16 + hi*4 + i;
    if (row < MM){ M[i] = PM[(size_t)b*MPAD+row]; rinv[i] = 1.f/PS[(size_t)b*MPAD+row]; }
    else { M[i] = 0.f; rinv[i] = 0.f; }
  }

  f32x4 acc[8];
  #pragma unroll
  for (int nt=0;nt<8;++nt) acc[nt] = f32x4{0.f,0.f,0.f,0.f};

  const int key0 = s*(NH/NSP);
  const size_t kbase = ((size_t)b*NSEQ + MM)*128;
  const size_t obase = (size_t)b*128*NH;

  bf16x8 fr[2][16];
  auto loadFr = [&](int kk, bf16x8* dst){
    #pragma unroll
    for (int t=0;t<2;++t)
      #pragma unroll
      for (int ks=0;ks<4;++ks)
        dst[t*4+ks] = *(const bf16x8*)(KB + kbase + (size_t)(kk + t*16 + lo)*128 + ks*32 + hi*8);
    #pragma unroll
    for (int nt=0;nt<8;++nt)
      dst[8+nt] = *(const bf16x8*)(OHT + obase + (size_t)(nt*16 + lo)*NH + kk + hi*8);
  };

  auto body = [&](bf16x8* cur, bf16x8* nxt, int c, bool pre){
    if (pre) loadFr(key0 + (c+1)*32, nxt);
    f32x4 s0 = {0.f,0.f,0.f,0.f}, s1 = {0.f,0.f,0.f,0.f};
    #pragma unroll
    for (int ks=0;ks<4;++ks){
      s0 = __builtin_amdgcn_mfma_f32_16x16x32_bf16(aq[ks], cur[ks],   s0, 0,0,0);
      s1 = __builtin_amdgcn_mfma_f32_16x16x32_bf16(aq[ks], cur[4+ks], s1, 0,0,0);
    }
    #pragma unroll
    for (int i=0;i<4;++i){
      float p0 = __expf(s0[i]-M[i]), p1 = __expf(s1[i]-M[i]);
      P_lds[hi*4+i][lo]    = f2bf(p0);
      P_lds[hi*4+i][lo+16] = f2bf(p1);
    }
    bf16x8 pa = *(const bf16x8*)&P_lds[lo][hi*8];
    #pragma unroll
    for (int nt=0;nt<8;++nt)
      acc[nt] = __builtin_amdgcn_mfma_f32_16x16x32_bf16(pa, cur[8+nt], acc[nt], 0,0,0);
  };

  loadFr(key0, fr[0]);
  for (int c = 0; c < (NH/NSP)/32; c += 2){
    body(fr[0], fr[1], c,   true);
    body(fr[1], fr[0], c+1, c+2 < (NH/NSP)/32);
  }

  size_t pb = ((size_t)(b*NSP + s)*MPAD + mt*16);
  #pragma unroll
  for (int nt=0;nt<8;++nt)
    #pragma unroll
    for (int i=0;i<4;++i)
      PACC[(pb + hi*4 + i)*128 + nt*16 + lo] = acc[nt][i]*rinv[i];
}

// ---------------- K6: deterministic reduction of xp partials into d_out ----------------
__global__ void k_xpreduce(const float* __restrict__ PACC, float* __restrict__ OUT){
  int b = blockIdx.x, m = blockIdx.y;   // m < 281
  int d = threadIdx.x;
  float a = 0.f;
  #pragma unroll
  for (int s=0;s<NSP;++s) a += PACC[(((size_t)b*NSP+s)*MPAD+m)*128+d];
  OUT[((size_t)b*NSEQ+m)*128+d] += a;
}

extern "C" void kernel_launch(void* const* d_in, const int* in_sizes, int n_in,
                              void* d_out, int out_size, void* d_ws, size_t ws_size,
                              hipStream_t stream){
  const float* x    = (const float*)d_in[0];
  const float* qW   = (const float*)d_in[1];
  const float* qb   = (const float*)d_in[2];
  const float* qA   = (const float*)d_in[3];
  const float* qB   = (const float*)d_in[4];
  const float* kvW  = (const float*)d_in[5];
  const float* kvb  = (const float*)d_in[6];
  const float* kvA  = (const float*)d_in[7];
  const float* kvB  = (const float*)d_in[8];
  const float* resW = (const float*)d_in[9];
  const float* resw = (const float*)d_in[10];
  float* out = (float*)d_out;

  char* base = (char*)d_ws;
  size_t off = 0;
  auto alloc = [&](size_t bytes) -> void* {
    void* p = base + off; off += (bytes + 255) & ~(size_t)255; return p;
  };
  float* Wc   = (float*)alloc(512*256*4);
  float* bc   = (float*)alloc(512*4);
  short* QB   = (short*)alloc((size_t)NTOT*128*2);
  short* KB   = (short*)alloc((size_t)NTOT*128*2);
  float* V    = (float*)alloc((size_t)NTOT*128*4);
  short* VTb  = (short*)alloc((size_t)BB*128*MPAD*2);
  short* OPTb = (short*)alloc((size_t)BB*128*MPAD*2);
  float* PM   = (float*)alloc((size_t)BB*MPAD*4);
  float* PS   = (float*)alloc((size_t)BB*MPAD*4);
  float* PACC = (float*)alloc((size_t)BB*NSP*MPAD*128*4);
  float* PMX  = (float*)alloc((size_t)BB*NSP*MPAD*4);
  float* PSM  = (float*)alloc((size_t)BB*NSP*MPAD*4);
  short* OHB  = (short*)alloc((size_t)BB*NH*128*2);
  short* OHT  = (short*)alloc((size_t)BB*128*NH*2);
  short* VhT  = (short*)alloc((size_t)BB*128*NH*2);
  (void)off; (void)ws_size; (void)in_sizes; (void)n_in; (void)out_size;

  k_weights<<<dim3(512), dim3(256), 0, stream>>>(qW,qb,qA,qB,kvW,kvb,kvA,kvB,resW,resw,Wc,bc);
  k_proj<<<dim3((NTOT+63)/64, 8), dim3(256), 0, stream>>>(x, Wc, bc, QB, KB, V, out);
  k_prep<<<dim3(BB, MPAD), dim3(128), 0, stream>>>(V, VTb, OPTb);
  k_transV<<<dim3(BB, NH/64, 2), dim3(256), 0, stream>>>(V, VhT);
  k_attnp2<<<dim3(18, NSP, BB), dim3(64), 0, stream>>>(QB, KB, VhT, PACC, PMX, PSM);
  k_pcombine<<<dim3(BB, MM), dim3(128), 0, stream>>>(PACC, PMX, PSM, PM, PS, OPTb);
  k_attnh2<<<dim3(BB, NH/64), dim3(256), 0, stream>>>(QB, KB, VTb, OPTb, OHB, out);
  k_transOH<<<dim3(BB, NH/64, 2), dim3(256), 0, stream>>>(OHB, OHT);
  k_xp2<<<dim3(18, NSP, BB), dim3(64), 0, stream>>>(QB, KB, OHT, PM, PS, PACC);
  k_xpreduce<<<dim3(BB, MM), dim3(128), 0, stream>>>(PACC, out);
}

// Round 4
// 849.412 us; speedup vs baseline: 41.8859x; 1.2894x over previous
//
#include <hip/hip_runtime.h>
#include <hip/hip_bf16.h>
#include <cstddef>

#define MM     281
#define NSEQ   33049
#define BB     4
#define NH     32768          // NSEQ - MM
#define NTOT   (BB*NSEQ)      // 132196
#define MPAD   288
#define NSP    32             // key splits for p-attention
#define SCALEQ 0.125f
#define LORAS  2.0f

typedef __attribute__((ext_vector_type(8))) short bf16x8;
typedef __attribute__((ext_vector_type(4))) float f32x4;

static __device__ __forceinline__ short f2bf(float v){
  __hip_bfloat16 h = __float2bfloat16(v);
  return *reinterpret_cast<short*>(&h);
}

// ---------------- K0: fold LoRA + scales into combined bf16 weight matrix ----------------
__global__ void k_weights(const float* __restrict__ qW, const float* __restrict__ qb,
                          const float* __restrict__ qA, const float* __restrict__ qB,
                          const float* __restrict__ kvW, const float* __restrict__ kvb,
                          const float* __restrict__ kvA, const float* __restrict__ kvB,
                          const float* __restrict__ resW, const float* __restrict__ resw,
                          short* __restrict__ WcB, float* __restrict__ bc){
  int j = blockIdx.x;     // 0..511
  int c = threadIdx.x;    // 0..255
  float w;
  if (j < 128){
    float l = 0.f;
    #pragma unroll
    for (int r = 0; r < 8; ++r) l += qA[j*8+r]*qB[r*256+c];
    w = SCALEQ*(qW[j*256+c] + LORAS*l);
    if (c==0) bc[j] = SCALEQ*qb[j];
  } else if (j < 384){
    int jj = j-128;
    float l = 0.f;
    #pragma unroll
    for (int r = 0; r < 8; ++r) l += kvA[jj*8+r]*kvB[r*256+c];
    w = kvW[jj*256+c] + LORAS*l;
    if (c==0) bc[j] = kvb[jj];
  } else {
    int jj = j-384;
    w = resw[0]*resW[jj*256+c];
    if (c==0) bc[j] = 0.f;
  }
  WcB[j*256+c] = f2bf(w);
}

// ---------------- K1: MFMA projection GEMM  Y = x @ Wc.T + bc ----------------
// BM=32, BN=512 (full). 4 waves; wave w owns cols [w*128, w*128+128).
// No LDS: A-frags converted f32->bf16 in-register; B-frags direct from L2-hot WcB.
__global__ __launch_bounds__(256) void k_proj2(const float* __restrict__ X,
                       const short* __restrict__ WcB, const float* __restrict__ bc,
                       short* __restrict__ QB, short* __restrict__ KB,
                       short* __restrict__ VB, float* __restrict__ OUT){
  int tid = threadIdx.x;
  int wid = tid >> 6, lane = tid & 63;
  int lo = lane & 15, hi = lane >> 4;
  int m0 = blockIdx.x*32;

  f32x4 acc[2][8];
  #pragma unroll
  for (int mt=0;mt<2;++mt)
    #pragma unroll
    for (int nt=0;nt<8;++nt) acc[mt][nt] = f32x4{0.f,0.f,0.f,0.f};

  int r0 = m0 + lo;      if (r0 >= NTOT) r0 = NTOT-1;
  int r1 = m0 + 16 + lo; if (r1 >= NTOT) r1 = NTOT-1;
  const float* x0p = X + (size_t)r0*256 + hi*8;
  const float* x1p = X + (size_t)r1*256 + hi*8;

  #pragma unroll
  for (int ks=0; ks<8; ++ks){
    bf16x8 a[2];
    {
      float4 u = *(const float4*)(x0p + ks*32);
      float4 v = *(const float4*)(x0p + ks*32 + 4);
      a[0] = bf16x8{f2bf(u.x),f2bf(u.y),f2bf(u.z),f2bf(u.w),
                    f2bf(v.x),f2bf(v.y),f2bf(v.z),f2bf(v.w)};
      u = *(const float4*)(x1p + ks*32);
      v = *(const float4*)(x1p + ks*32 + 4);
      a[1] = bf16x8{f2bf(u.x),f2bf(u.y),f2bf(u.z),f2bf(u.w),
                    f2bf(v.x),f2bf(v.y),f2bf(v.z),f2bf(v.w)};
    }
    bf16x8 bfr[8];
    #pragma unroll
    for (int nt=0;nt<8;++nt){
      int jc = wid*128 + nt*16 + lo;
      bfr[nt] = *(const bf16x8*)(WcB + (size_t)jc*256 + ks*32 + hi*8);
    }
    #pragma unroll
    for (int nt=0;nt<8;++nt){
      acc[0][nt] = __builtin_amdgcn_mfma_f32_16x16x32_bf16(a[0], bfr[nt], acc[0][nt], 0,0,0);
      acc[1][nt] = __builtin_amdgcn_mfma_f32_16x16x32_bf16(a[1], bfr[nt], acc[1][nt], 0,0,0);
    }
  }

  float bias[8];
  #pragma unroll
  for (int nt=0;nt<8;++nt) bias[nt] = bc[wid*128 + nt*16 + lo];

  #pragma unroll
  for (int mt=0;mt<2;++mt){
    #pragma unroll
    for (int i=0;i<4;++i){
      int row = m0 + mt*16 + hi*4 + i;
      if (row >= NTOT) continue;
      #pragma unroll
      for (int nt=0;nt<8;++nt){
        float v = acc[mt][nt][i] + bias[nt];
        int col = nt*16 + lo;   // within this wave's 128-col slab
        if      (wid == 0) QB[(size_t)row*128 + col] = f2bf(v);
        else if (wid == 1) KB[(size_t)row*128 + col] = f2bf(v);
        else if (wid == 2) VB[(size_t)row*128 + col] = f2bf(v);
        else               OUT[(size_t)row*128 + col] = v;
      }
    }
  }
}

// ---------------- K1b: V_p^T bf16 (padded) + zero-pad of OP^T tail ----------------
__global__ void k_prep(const short* __restrict__ VB, short* __restrict__ VTb,
                       short* __restrict__ OPTb){
  int b = blockIdx.x, m = blockIdx.y, d = threadIdx.x;  // m<288, d<128
  short vv = (m < MM) ? VB[((size_t)b*NSEQ + m)*128 + d] : (short)0;
  VTb[((size_t)b*128 + d)*MPAD + m] = vv;
  if (m >= MM) OPTb[((size_t)b*128 + d)*MPAD + m] = 0;
}

// ---------------- K1c: transpose V_h bf16 -> VhT bf16 [b][128][NH] ----------------
__global__ __launch_bounds__(256) void k_transV(const short* __restrict__ VB,
                                                short* __restrict__ VhT){
  __shared__ short t[64][74];
  int b = blockIdx.x, k0 = blockIdx.y*64, d0 = blockIdx.z*64;
  int tid = threadIdx.x;
  #pragma unroll
  for (int i=0;i<16;++i){
    int idx = tid + 256*i; int r = idx>>6, c = idx&63;
    t[r][c] = VB[((size_t)b*NSEQ + MM + k0 + r)*128 + d0 + c];
  }
  __syncthreads();
  #pragma unroll
  for (int i=0;i<16;++i){
    int idx = tid + 256*i; int r = idx>>6, c = idx&63;  // r: d, c: key
    VhT[((size_t)b*128 + d0 + r)*NH + k0 + c] = t[c][r];
  }
}

// ---------------- K1d: transpose OHB bf16 -> OHT bf16 [b][128][NH] ----------------
__global__ __launch_bounds__(256) void k_transOH(const short* __restrict__ OHB,
                                                 short* __restrict__ OHT){
  __shared__ short t[64][74];
  int b = blockIdx.x, k0 = blockIdx.y*64, d0 = blockIdx.z*64;
  int tid = threadIdx.x;
  #pragma unroll
  for (int i=0;i<16;++i){
    int idx = tid + 256*i; int r = idx>>6, c = idx&63;
    t[r][c] = OHB[((size_t)b*NH + k0 + r)*128 + d0 + c];
  }
  __syncthreads();
  #pragma unroll
  for (int i=0;i<16;++i){
    int idx = tid + 256*i; int r = idx>>6, c = idx&63;  // r: d, c: key
    OHT[((size_t)b*128 + d0 + r)*NH + k0 + c] = t[c][r];
  }
}

// ---------------- K2: MFMA flash attn_p partials (split over keys) ----------------
__global__ __launch_bounds__(64) void k_attnp2(const short* __restrict__ QB,
                        const short* __restrict__ KB, const short* __restrict__ VhT,
                        float* __restrict__ PACC, float* __restrict__ PMX,
                        float* __restrict__ PSM){
  __shared__ short P_lds[16][40];
  int lane = threadIdx.x;
  int lo = lane & 15, hi = lane >> 4;
  int mt = blockIdx.x;   // 0..17
  int s  = blockIdx.y;   // 0..NSP-1
  int b  = blockIdx.z;

  bf16x8 aq[4];
  int qrow = mt*16 + lo;
  if (qrow < MM){
    size_t qb = ((size_t)b*NSEQ + qrow)*128;
    #pragma unroll
    for (int ks=0;ks<4;++ks) aq[ks] = *(const bf16x8*)(QB + qb + ks*32 + hi*8);
  } else {
    #pragma unroll
    for (int ks=0;ks<4;++ks) aq[ks] = bf16x8{0,0,0,0,0,0,0,0};
  }

  float rmax[4], rsum[4];
  #pragma unroll
  for (int i=0;i<4;++i){ rmax[i] = -1e30f; rsum[i] = 0.f; }
  f32x4 acc[8];
  #pragma unroll
  for (int nt=0;nt<8;++nt) acc[nt] = f32x4{0.f,0.f,0.f,0.f};

  const int key0 = s*(NH/NSP);            // 1024 keys per split
  const size_t kbase = ((size_t)b*NSEQ + MM)*128;
  const size_t vbase = (size_t)b*128*NH;

  bf16x8 fr[2][16];
  auto loadFr = [&](int kk, bf16x8* dst){
    #pragma unroll
    for (int t=0;t<2;++t)
      #pragma unroll
      for (int ks=0;ks<4;++ks)
        dst[t*4+ks] = *(const bf16x8*)(KB + kbase + (size_t)(kk + t*16 + lo)*128 + ks*32 + hi*8);
    #pragma unroll
    for (int nt=0;nt<8;++nt)
      dst[8+nt] = *(const bf16x8*)(VhT + vbase + (size_t)(nt*16 + lo)*NH + kk + hi*8);
  };

  auto body = [&](bf16x8* cur, bf16x8* nxt, int c, bool pre){
    if (pre) loadFr(key0 + (c+1)*32, nxt);
    f32x4 s0 = {0.f,0.f,0.f,0.f}, s1 = {0.f,0.f,0.f,0.f};
    #pragma unroll
    for (int ks=0;ks<4;++ks){
      s0 = __builtin_amdgcn_mfma_f32_16x16x32_bf16(aq[ks], cur[ks],   s0, 0,0,0);
      s1 = __builtin_amdgcn_mfma_f32_16x16x32_bf16(aq[ks], cur[4+ks], s1, 0,0,0);
    }
    #pragma unroll
    for (int i=0;i<4;++i){
      float mc = fmaxf(s0[i], s1[i]);
      #pragma unroll
      for (int d=1; d<16; d<<=1) mc = fmaxf(mc, __shfl_xor(mc, d));
      float mnew = fmaxf(rmax[i], mc);
      float scale = __expf(rmax[i]-mnew);
      float p0 = __expf(s0[i]-mnew), p1 = __expf(s1[i]-mnew);
      rsum[i] = rsum[i]*scale + p0 + p1;
      rmax[i] = mnew;
      #pragma unroll
      for (int nt=0;nt<8;++nt) acc[nt][i] *= scale;
      P_lds[hi*4+i][lo]    = f2bf(p0);
      P_lds[hi*4+i][lo+16] = f2bf(p1);
    }
    bf16x8 pa = *(const bf16x8*)&P_lds[lo][hi*8];
    #pragma unroll
    for (int nt=0;nt<8;++nt)
      acc[nt] = __builtin_amdgcn_mfma_f32_16x16x32_bf16(pa, cur[8+nt], acc[nt], 0,0,0);
  };

  loadFr(key0, fr[0]);
  for (int c = 0; c < (NH/NSP)/32; c += 2){
    body(fr[0], fr[1], c,   true);
    body(fr[1], fr[0], c+1, c+2 < (NH/NSP)/32);
  }

  #pragma unroll
  for (int i=0;i<4;++i){
    #pragma unroll
    for (int d=1; d<16; d<<=1) rsum[i] += __shfl_xor(rsum[i], d);
  }
  size_t pb = ((size_t)(b*NSP + s)*MPAD + mt*16);
  #pragma unroll
  for (int nt=0;nt<8;++nt)
    #pragma unroll
    for (int i=0;i<4;++i)
      PACC[(pb + hi*4 + i)*128 + nt*16 + lo] = acc[nt][i];
  if (lo == 0){
    #pragma unroll
    for (int i=0;i<4;++i){
      PMX[pb + hi*4 + i] = rmax[i];
      PSM[pb + hi*4 + i] = rsum[i];
    }
  }
}

// ---------------- K3: combine attn_p splits -> OP^T bf16 + final stats ----------------
__global__ void k_pcombine(const float* __restrict__ PACC, const float* __restrict__ PMX,
                           const float* __restrict__ PSM,
                           float* __restrict__ PM, float* __restrict__ PS,
                           short* __restrict__ OPTb){
  int b = blockIdx.x, m = blockIdx.y;   // m < 281
  int d = threadIdx.x;                  // 0..127
  float M = -1e30f;
  #pragma unroll
  for (int s=0;s<NSP;++s) M = fmaxf(M, PMX[((size_t)b*NSP+s)*MPAD+m]);
  float sum = 0.f, a = 0.f;
  #pragma unroll
  for (int s=0;s<NSP;++s){
    size_t pb = ((size_t)b*NSP+s)*MPAD+m;
    float e = __expf(PMX[pb]-M);
    sum += PSM[pb]*e;
    a   += PACC[pb*128+d]*e;
  }
  OPTb[((size_t)b*128+d)*MPAD+m] = f2bf(a/sum);
  if (d==0){ PM[(size_t)b*MPAD+m]=M; PS[(size_t)b*MPAD+m]=sum; }
}

// ---------------- K4: attn_h via MFMA: S=Q·Kp^T -> reg softmax -> out_h & xh ----------
__global__ __launch_bounds__(256) void k_attnh2(const short* __restrict__ QB,
                        const short* __restrict__ KB,
                        const short* __restrict__ VTb,
                        const short* __restrict__ OPTb,
                        short* __restrict__ OHB, float* __restrict__ OUT){
  __shared__ short P_lds[4][16][296];
  int tid = threadIdx.x;
  int wid = tid >> 6, lane = tid & 63;
  int lo = lane & 15, hi = lane >> 4;
  int b = blockIdx.x;
  int q0 = blockIdx.y*64 + wid*16;   // q row within h-block [0,NH)

  bf16x8 aq[4];
  size_t qrow = ((size_t)b*NSEQ + MM + q0 + lo)*128;
  #pragma unroll
  for (int ks=0;ks<4;++ks) aq[ks] = *(const bf16x8*)(QB + qrow + ks*32 + hi*8);

  f32x4 s[18];
  #pragma unroll
  for (int nt=0;nt<18;++nt){
    f32x4 acc = {0.f,0.f,0.f,0.f};
    size_t krow = ((size_t)b*NSEQ + nt*16 + lo)*128;
    #pragma unroll
    for (int ks=0;ks<4;++ks){
      bf16x8 bk = *(const bf16x8*)(KB + krow + ks*32 + hi*8);
      acc = __builtin_amdgcn_mfma_f32_16x16x32_bf16(aq[ks], bk, acc, 0,0,0);
    }
    s[nt] = acc;
  }
  if (lo >= 9){
    s[17][0] = -1e30f; s[17][1] = -1e30f; s[17][2] = -1e30f; s[17][3] = -1e30f;
  }
  #pragma unroll
  for (int i=0;i<4;++i){
    float m = -1e30f;
    #pragma unroll
    for (int nt=0;nt<18;++nt) m = fmaxf(m, s[nt][i]);
    #pragma unroll
    for (int d=1; d<16; d<<=1) m = fmaxf(m, __shfl_xor(m, d));
    float ss = 0.f;
    #pragma unroll
    for (int nt=0;nt<18;++nt){ float w = __expf(s[nt][i]-m); s[nt][i] = w; ss += w; }
    #pragma unroll
    for (int d=1; d<16; d<<=1) ss += __shfl_xor(ss, d);
    float rinv = 1.f/ss;
    int r = hi*4 + i;
    #pragma unroll
    for (int nt=0;nt<18;++nt) P_lds[wid][r][nt*16+lo] = f2bf(s[nt][i]*rinv);
  }
  bf16x8 pa[9];
  #pragma unroll
  for (int ks=0;ks<9;++ks) pa[ks] = *(const bf16x8*)&P_lds[wid][lo][ks*32 + hi*8];

  #pragma unroll
  for (int nt=0; nt<8; ++nt){
    f32x4 aoh = {0.f,0.f,0.f,0.f};
    f32x4 axh = {0.f,0.f,0.f,0.f};
    size_t vrow = ((size_t)b*128 + nt*16 + lo)*MPAD;
    #pragma unroll
    for (int ks=0;ks<9;++ks){
      bf16x8 bv = *(const bf16x8*)(VTb + vrow + ks*32 + hi*8);
      aoh = __builtin_amdgcn_mfma_f32_16x16x32_bf16(pa[ks], bv, aoh, 0,0,0);
      bf16x8 bo = *(const bf16x8*)(OPTb + vrow + ks*32 + hi*8);
      axh = __builtin_amdgcn_mfma_f32_16x16x32_bf16(pa[ks], bo, axh, 0,0,0);
    }
    #pragma unroll
    for (int i=0;i<4;++i){
      size_t rq = (size_t)q0 + hi*4 + i;
      int d = nt*16 + lo;
      OHB[((size_t)b*NH + rq)*128 + d] = f2bf(aoh[i]);
      size_t oo = ((size_t)b*NSEQ + MM + rq)*128 + d;
      OUT[oo] += axh[i];
    }
  }
}

// ---------------- K5: xp partials = attn_p @ out_h via MFMA (recomputed weights) -------
__global__ __launch_bounds__(64) void k_xp2(const short* __restrict__ QB,
                     const short* __restrict__ KB, const short* __restrict__ OHT,
                     const float* __restrict__ PM, const float* __restrict__ PS,
                     float* __restrict__ PACC){
  __shared__ short P_lds[16][40];
  int lane = threadIdx.x;
  int lo = lane & 15, hi = lane >> 4;
  int mt = blockIdx.x;   // 0..17
  int s  = blockIdx.y;   // 0..NSP-1
  int b  = blockIdx.z;

  bf16x8 aq[4];
  int qrow = mt*16 + lo;
  if (qrow < MM){
    size_t qb = ((size_t)b*NSEQ + qrow)*128;
    #pragma unroll
    for (int ks=0;ks<4;++ks) aq[ks] = *(const bf16x8*)(QB + qb + ks*32 + hi*8);
  } else {
    #pragma unroll
    for (int ks=0;ks<4;++ks) aq[ks] = bf16x8{0,0,0,0,0,0,0,0};
  }

  float M[4], rinv[4];
  #pragma unroll
  for (int i=0;i<4;++i){
    int row = mt*16 + hi*4 + i;
    if (row < MM){ M[i] = PM[(size_t)b*MPAD+row]; rinv[i] = 1.f/PS[(size_t)b*MPAD+row]; }
    else { M[i] = 0.f; rinv[i] = 0.f; }
  }

  f32x4 acc[8];
  #pragma unroll
  for (int nt=0;nt<8;++nt) acc[nt] = f32x4{0.f,0.f,0.f,0.f};

  const int key0 = s*(NH/NSP);
  const size_t kbase = ((size_t)b*NSEQ + MM)*128;
  const size_t obase = (size_t)b*128*NH;

  bf16x8 fr[2][16];
  auto loadFr = [&](int kk, bf16x8* dst){
    #pragma unroll
    for (int t=0;t<2;++t)
      #pragma unroll
      for (int ks=0;ks<4;++ks)
        dst[t*4+ks] = *(const bf16x8*)(KB + kbase + (size_t)(kk + t*16 + lo)*128 + ks*32 + hi*8);
    #pragma unroll
    for (int nt=0;nt<8;++nt)
      dst[8+nt] = *(const bf16x8*)(OHT + obase + (size_t)(nt*16 + lo)*NH + kk + hi*8);
  };

  auto body = [&](bf16x8* cur, bf16x8* nxt, int c, bool pre){
    if (pre) loadFr(key0 + (c+1)*32, nxt);
    f32x4 s0 = {0.f,0.f,0.f,0.f}, s1 = {0.f,0.f,0.f,0.f};
    #pragma unroll
    for (int ks=0;ks<4;++ks){
      s0 = __builtin_amdgcn_mfma_f32_16x16x32_bf16(aq[ks], cur[ks],   s0, 0,0,0);
      s1 = __builtin_amdgcn_mfma_f32_16x16x32_bf16(aq[ks], cur[4+ks], s1, 0,0,0);
    }
    #pragma unroll
    for (int i=0;i<4;++i){
      float p0 = __expf(s0[i]-M[i]), p1 = __expf(s1[i]-M[i]);
      P_lds[hi*4+i][lo]    = f2bf(p0);
      P_lds[hi*4+i][lo+16] = f2bf(p1);
    }
    bf16x8 pa = *(const bf16x8*)&P_lds[lo][hi*8];
    #pragma unroll
    for (int nt=0;nt<8;++nt)
      acc[nt] = __builtin_amdgcn_mfma_f32_16x16x32_bf16(pa, cur[8+nt], acc[nt], 0,0,0);
  };

  loadFr(key0, fr[0]);
  for (int c = 0; c < (NH/NSP)/32; c += 2){
    body(fr[0], fr[1], c,   true);
    body(fr[1], fr[0], c+1, c+2 < (NH/NSP)/32);
  }

  size_t pb = ((size_t)(b*NSP + s)*MPAD + mt*16);
  #pragma unroll
  for (int nt=0;nt<8;++nt)
    #pragma unroll
    for (int i=0;i<4;++i)
      PACC[(pb + hi*4 + i)*128 + nt*16 + lo] = acc[nt][i]*rinv[i];
}

// ---------------- K6: deterministic reduction of xp partials into d_out ----------------
__global__ void k_xpreduce(const float* __restrict__ PACC, float* __restrict__ OUT){
  int b = blockIdx.x, m = blockIdx.y;   // m < 281
  int d = threadIdx.x;
  float a = 0.f;
  #pragma unroll
  for (int s=0;s<NSP;++s) a += PACC[(((size_t)b*NSP+s)*MPAD+m)*128+d];
  OUT[((size_t)b*NSEQ+m)*128+d] += a;
}

extern "C" void kernel_launch(void* const* d_in, const int* in_sizes, int n_in,
                              void* d_out, int out_size, void* d_ws, size_t ws_size,
                              hipStream_t stream){
  const float* x    = (const float*)d_in[0];
  const float* qW   = (const float*)d_in[1];
  const float* qb   = (const float*)d_in[2];
  const float* qA   = (const float*)d_in[3];
  const float* qB   = (const float*)d_in[4];
  const float* kvW  = (const float*)d_in[5];
  const float* kvb  = (const float*)d_in[6];
  const float* kvA  = (const float*)d_in[7];
  const float* kvB  = (const float*)d_in[8];
  const float* resW = (const float*)d_in[9];
  const float* resw = (const float*)d_in[10];
  float* out = (float*)d_out;

  char* base = (char*)d_ws;
  size_t off = 0;
  auto alloc = [&](size_t bytes) -> void* {
    void* p = base + off; off += (bytes + 255) & ~(size_t)255; return p;
  };
  short* WcB  = (short*)alloc(512*256*2);
  float* bc   = (float*)alloc(512*4);
  short* QB   = (short*)alloc((size_t)NTOT*128*2);
  short* KB   = (short*)alloc((size_t)NTOT*128*2);
  short* VB   = (short*)alloc((size_t)NTOT*128*2);
  short* VTb  = (short*)alloc((size_t)BB*128*MPAD*2);
  short* OPTb = (short*)alloc((size_t)BB*128*MPAD*2);
  float* PM   = (float*)alloc((size_t)BB*MPAD*4);
  float* PS   = (float*)alloc((size_t)BB*MPAD*4);
  float* PACC = (float*)alloc((size_t)BB*NSP*MPAD*128*4);
  float* PMX  = (float*)alloc((size_t)BB*NSP*MPAD*4);
  float* PSM  = (float*)alloc((size_t)BB*NSP*MPAD*4);
  short* OHB  = (short*)alloc((size_t)BB*NH*128*2);
  short* OHT  = (short*)alloc((size_t)BB*128*NH*2);
  short* VhT  = (short*)alloc((size_t)BB*128*NH*2);
  (void)off; (void)ws_size; (void)in_sizes; (void)n_in; (void)out_size;

  k_weights<<<dim3(512), dim3(256), 0, stream>>>(qW,qb,qA,qB,kvW,kvb,kvA,kvB,resW,resw,WcB,bc);
  k_proj2<<<dim3((NTOT+31)/32), dim3(256), 0, stream>>>(x, WcB, bc, QB, KB, VB, out);
  k_prep<<<dim3(BB, MPAD), dim3(128), 0, stream>>>(VB, VTb, OPTb);
  k_transV<<<dim3(BB, NH/64, 2), dim3(256), 0, stream>>>(VB, VhT);
  k_attnp2<<<dim3(18, NSP, BB), dim3(64), 0, stream>>>(QB, KB, VhT, PACC, PMX, PSM);
  k_pcombine<<<dim3(BB, MM), dim3(128), 0, stream>>>(PACC, PMX, PSM, PM, PS, OPTb);
  k_attnh2<<<dim3(BB, NH/64), dim3(256), 0, stream>>>(QB, KB, VTb, OPTb, OHB, out);
  k_transOH<<<dim3(BB, NH/64, 2), dim3(256), 0, stream>>>(OHB, OHT);
  k_xp2<<<dim3(18, NSP, BB), dim3(64), 0, stream>>>(QB, KB, OHT, PM, PS, PACC);
  k_xpreduce<<<dim3(BB, MM), dim3(128), 0, stream>>>(PACC, out);
}

// Round 5
// 783.560 us; speedup vs baseline: 45.4061x; 1.0840x over previous
//
#include <hip/hip_runtime.h>
#include <hip/hip_bf16.h>
#include <cstddef>

#define MM     281
#define NSEQ   33049
#define BB     4
#define NH     32768          // NSEQ - MM
#define NTOT   (BB*NSEQ)      // 132196
#define MPAD   288
#define NSP    32             // key splits for p-attention
#define SCALEQ 0.125f
#define LORAS  2.0f

typedef __attribute__((ext_vector_type(8))) short bf16x8;
typedef __attribute__((ext_vector_type(4))) float f32x4;

static __device__ __forceinline__ short f2bf(float v){
  __hip_bfloat16 h = __float2bfloat16(v);
  return *reinterpret_cast<short*>(&h);
}

// ---------------- K0: fold LoRA + scales into combined bf16 weight matrix ----------------
__global__ void k_weights(const float* __restrict__ qW, const float* __restrict__ qb,
                          const float* __restrict__ qA, const float* __restrict__ qB,
                          const float* __restrict__ kvW, const float* __restrict__ kvb,
                          const float* __restrict__ kvA, const float* __restrict__ kvB,
                          const float* __restrict__ resW, const float* __restrict__ resw,
                          short* __restrict__ WcB, float* __restrict__ bc){
  int j = blockIdx.x;     // 0..511
  int c = threadIdx.x;    // 0..255
  float w;
  if (j < 128){
    float l = 0.f;
    #pragma unroll
    for (int r = 0; r < 8; ++r) l += qA[j*8+r]*qB[r*256+c];
    w = SCALEQ*(qW[j*256+c] + LORAS*l);
    if (c==0) bc[j] = SCALEQ*qb[j];
  } else if (j < 384){
    int jj = j-128;
    float l = 0.f;
    #pragma unroll
    for (int r = 0; r < 8; ++r) l += kvA[jj*8+r]*kvB[r*256+c];
    w = kvW[jj*256+c] + LORAS*l;
    if (c==0) bc[j] = kvb[jj];
  } else {
    int jj = j-384;
    w = resw[0]*resW[jj*256+c];
    if (c==0) bc[j] = 0.f;
  }
  WcB[j*256+c] = f2bf(w);
}

// ---------------- K0b: X f32 -> bf16 (streaming) ----------------
__global__ __launch_bounds__(256) void k_cvtx(const float* __restrict__ X,
                                              short* __restrict__ XB){
  size_t i = ((size_t)blockIdx.x*256 + threadIdx.x)*8;
  if (i >= (size_t)NTOT*256) return;
  float4 u = *(const float4*)(X+i);
  float4 v = *(const float4*)(X+i+4);
  bf16x8 o = bf16x8{f2bf(u.x),f2bf(u.y),f2bf(u.z),f2bf(u.w),
                    f2bf(v.x),f2bf(v.y),f2bf(v.z),f2bf(v.w)};
  *(bf16x8*)(XB+i) = o;
}

// ---------------- K1: MFMA projection GEMM  Y = xb @ Wc.T + bc ----------------
// BM=32, BN=512. 4 waves; wave w owns cols [w*128, w*128+128).
// wave0->QB, wave1->KB, wave2->VB(p-rows)/VhT(h-rows transposed), wave3->OUT(res).
__global__ __launch_bounds__(256) void k_proj3(const short* __restrict__ XB,
                       const short* __restrict__ WcB, const float* __restrict__ bc,
                       short* __restrict__ QB, short* __restrict__ KB,
                       short* __restrict__ VB, short* __restrict__ VhT,
                       float* __restrict__ OUT){
  int tid = threadIdx.x;
  int wid = tid >> 6, lane = tid & 63;
  int lo = lane & 15, hi = lane >> 4;
  int m0 = blockIdx.x*32;

  f32x4 acc[2][8];
  #pragma unroll
  for (int mt=0;mt<2;++mt)
    #pragma unroll
    for (int nt=0;nt<8;++nt) acc[mt][nt] = f32x4{0.f,0.f,0.f,0.f};

  int r0 = m0 + lo;      if (r0 >= NTOT) r0 = NTOT-1;
  int r1 = m0 + 16 + lo; if (r1 >= NTOT) r1 = NTOT-1;
  const short* x0p = XB + (size_t)r0*256 + hi*8;
  const short* x1p = XB + (size_t)r1*256 + hi*8;

  #pragma unroll
  for (int ks=0; ks<8; ++ks){
    bf16x8 a0 = *(const bf16x8*)(x0p + ks*32);
    bf16x8 a1 = *(const bf16x8*)(x1p + ks*32);
    bf16x8 bfr[8];
    #pragma unroll
    for (int nt=0;nt<8;++nt){
      int jc = wid*128 + nt*16 + lo;
      bfr[nt] = *(const bf16x8*)(WcB + (size_t)jc*256 + ks*32 + hi*8);
    }
    #pragma unroll
    for (int nt=0;nt<8;++nt){
      acc[0][nt] = __builtin_amdgcn_mfma_f32_16x16x32_bf16(a0, bfr[nt], acc[0][nt], 0,0,0);
      acc[1][nt] = __builtin_amdgcn_mfma_f32_16x16x32_bf16(a1, bfr[nt], acc[1][nt], 0,0,0);
    }
  }

  float bias[8];
  #pragma unroll
  for (int nt=0;nt<8;++nt) bias[nt] = bc[wid*128 + nt*16 + lo];

  if (wid == 2){
    // V: p-rows -> VB row-major; h-rows -> VhT [b][128][NH] transposed (short4 over rows)
    #pragma unroll
    for (int mt=0;mt<2;++mt){
      int rbase = m0 + mt*16 + hi*4;
      int b = rbase / NSEQ;
      int m = rbase - b*NSEQ;
      bool fast = (rbase + 3 < NTOT) && (m >= MM) && (m + 4 <= NSEQ);
      #pragma unroll
      for (int nt=0;nt<8;++nt){
        int col = nt*16 + lo;
        float v0 = acc[mt][nt][0]+bias[nt], v1 = acc[mt][nt][1]+bias[nt];
        float v2 = acc[mt][nt][2]+bias[nt], v3 = acc[mt][nt][3]+bias[nt];
        if (fast){
          short4 o; o.x=f2bf(v0); o.y=f2bf(v1); o.z=f2bf(v2); o.w=f2bf(v3);
          *(short4*)&VhT[((size_t)b*128 + col)*NH + (m - MM)] = o;
        } else {
          float vv[4] = {v0,v1,v2,v3};
          #pragma unroll
          for (int i=0;i<4;++i){
            int row = rbase + i;
            if (row >= NTOT) continue;
            int bb = row / NSEQ;
            int mm = row - bb*NSEQ;
            if (mm < MM) VB[((size_t)bb*NSEQ + mm)*128 + col] = f2bf(vv[i]);
            else         VhT[((size_t)bb*128 + col)*NH + (mm - MM)] = f2bf(vv[i]);
          }
        }
      }
    }
  } else {
    #pragma unroll
    for (int mt=0;mt<2;++mt){
      #pragma unroll
      for (int i=0;i<4;++i){
        int row = m0 + mt*16 + hi*4 + i;
        if (row >= NTOT) continue;
        #pragma unroll
        for (int nt=0;nt<8;++nt){
          float v = acc[mt][nt][i] + bias[nt];
          int col = nt*16 + lo;
          if      (wid == 0) QB[(size_t)row*128 + col] = f2bf(v);
          else if (wid == 1) KB[(size_t)row*128 + col] = f2bf(v);
          else               OUT[(size_t)row*128 + col] = v;
        }
      }
    }
  }
}

// ---------------- K1b: V_p^T bf16 (padded) + zero-pad of OP^T tail ----------------
__global__ void k_prep(const short* __restrict__ VB, short* __restrict__ VTb,
                       short* __restrict__ OPTb){
  int b = blockIdx.x, m = blockIdx.y, d = threadIdx.x;  // m<288, d<128
  short vv = (m < MM) ? VB[((size_t)b*NSEQ + m)*128 + d] : (short)0;
  VTb[((size_t)b*128 + d)*MPAD + m] = vv;
  if (m >= MM) OPTb[((size_t)b*128 + d)*MPAD + m] = 0;
}

// ---------------- K2: MFMA flash attn_p partials (split over keys) ----------------
__global__ __launch_bounds__(64) void k_attnp2(const short* __restrict__ QB,
                        const short* __restrict__ KB, const short* __restrict__ VhT,
                        float* __restrict__ PACC, float* __restrict__ PMX,
                        float* __restrict__ PSM){
  __shared__ short P_lds[16][40];
  int lane = threadIdx.x;
  int lo = lane & 15, hi = lane >> 4;
  int mt = blockIdx.x;   // 0..17
  int s  = blockIdx.y;   // 0..NSP-1
  int b  = blockIdx.z;

  bf16x8 aq[4];
  int qrow = mt*16 + lo;
  if (qrow < MM){
    size_t qb = ((size_t)b*NSEQ + qrow)*128;
    #pragma unroll
    for (int ks=0;ks<4;++ks) aq[ks] = *(const bf16x8*)(QB + qb + ks*32 + hi*8);
  } else {
    #pragma unroll
    for (int ks=0;ks<4;++ks) aq[ks] = bf16x8{0,0,0,0,0,0,0,0};
  }

  float rmax[4], rsum[4];
  #pragma unroll
  for (int i=0;i<4;++i){ rmax[i] = -1e30f; rsum[i] = 0.f; }
  f32x4 acc[8];
  #pragma unroll
  for (int nt=0;nt<8;++nt) acc[nt] = f32x4{0.f,0.f,0.f,0.f};

  const int key0 = s*(NH/NSP);            // 1024 keys per split
  const size_t kbase = ((size_t)b*NSEQ + MM)*128;
  const size_t vbase = (size_t)b*128*NH;

  bf16x8 fr[2][16];
  auto loadFr = [&](int kk, bf16x8* dst){
    #pragma unroll
    for (int t=0;t<2;++t)
      #pragma unroll
      for (int ks=0;ks<4;++ks)
        dst[t*4+ks] = *(const bf16x8*)(KB + kbase + (size_t)(kk + t*16 + lo)*128 + ks*32 + hi*8);
    #pragma unroll
    for (int nt=0;nt<8;++nt)
      dst[8+nt] = *(const bf16x8*)(VhT + vbase + (size_t)(nt*16 + lo)*NH + kk + hi*8);
  };

  auto body = [&](bf16x8* cur, bf16x8* nxt, int c, bool pre){
    if (pre) loadFr(key0 + (c+1)*32, nxt);
    f32x4 s0 = {0.f,0.f,0.f,0.f}, s1 = {0.f,0.f,0.f,0.f};
    #pragma unroll
    for (int ks=0;ks<4;++ks){
      s0 = __builtin_amdgcn_mfma_f32_16x16x32_bf16(aq[ks], cur[ks],   s0, 0,0,0);
      s1 = __builtin_amdgcn_mfma_f32_16x16x32_bf16(aq[ks], cur[4+ks], s1, 0,0,0);
    }
    #pragma unroll
    for (int i=0;i<4;++i){
      float mc = fmaxf(s0[i], s1[i]);
      #pragma unroll
      for (int d=1; d<16; d<<=1) mc = fmaxf(mc, __shfl_xor(mc, d));
      float mnew = fmaxf(rmax[i], mc);
      float scale = __expf(rmax[i]-mnew);
      float p0 = __expf(s0[i]-mnew), p1 = __expf(s1[i]-mnew);
      rsum[i] = rsum[i]*scale + p0 + p1;
      rmax[i] = mnew;
      #pragma unroll
      for (int nt=0;nt<8;++nt) acc[nt][i] *= scale;
      P_lds[hi*4+i][lo]    = f2bf(p0);
      P_lds[hi*4+i][lo+16] = f2bf(p1);
    }
    bf16x8 pa = *(const bf16x8*)&P_lds[lo][hi*8];
    #pragma unroll
    for (int nt=0;nt<8;++nt)
      acc[nt] = __builtin_amdgcn_mfma_f32_16x16x32_bf16(pa, cur[8+nt], acc[nt], 0,0,0);
  };

  loadFr(key0, fr[0]);
  for (int c = 0; c < (NH/NSP)/32; c += 2){
    body(fr[0], fr[1], c,   true);
    body(fr[1], fr[0], c+1, c+2 < (NH/NSP)/32);
  }

  #pragma unroll
  for (int i=0;i<4;++i){
    #pragma unroll
    for (int d=1; d<16; d<<=1) rsum[i] += __shfl_xor(rsum[i], d);
  }
  size_t pb = ((size_t)(b*NSP + s)*MPAD + mt*16);
  #pragma unroll
  for (int nt=0;nt<8;++nt)
    #pragma unroll
    for (int i=0;i<4;++i)
      PACC[(pb + hi*4 + i)*128 + nt*16 + lo] = acc[nt][i];
  if (lo == 0){
    #pragma unroll
    for (int i=0;i<4;++i){
      PMX[pb + hi*4 + i] = rmax[i];
      PSM[pb + hi*4 + i] = rsum[i];
    }
  }
}

// ---------------- K3: combine attn_p splits -> OP^T bf16 + final stats ----------------
__global__ void k_pcombine(const float* __restrict__ PACC, const float* __restrict__ PMX,
                           const float* __restrict__ PSM,
                           float* __restrict__ PM, float* __restrict__ PS,
                           short* __restrict__ OPTb){
  int b = blockIdx.x, m = blockIdx.y;   // m < 281
  int d = threadIdx.x;                  // 0..127
  float M = -1e30f;
  #pragma unroll
  for (int s=0;s<NSP;++s) M = fmaxf(M, PMX[((size_t)b*NSP+s)*MPAD+m]);
  float sum = 0.f, a = 0.f;
  #pragma unroll
  for (int s=0;s<NSP;++s){
    size_t pb = ((size_t)b*NSP+s)*MPAD+m;
    float e = __expf(PMX[pb]-M);
    sum += PSM[pb]*e;
    a   += PACC[pb*128+d]*e;
  }
  OPTb[((size_t)b*128+d)*MPAD+m] = f2bf(a/sum);
  if (d==0){ PM[(size_t)b*MPAD+m]=M; PS[(size_t)b*MPAD+m]=sum; }
}

// ---------------- K4: attn_h via MFMA: S=Q·Kp^T -> reg softmax -> out_h & xh ----------
// writes OHT [b][128][NH] directly (transposed short4 stores)
__global__ __launch_bounds__(256) void k_attnh2(const short* __restrict__ QB,
                        const short* __restrict__ KB,
                        const short* __restrict__ VTb,
                        const short* __restrict__ OPTb,
                        short* __restrict__ OHT, float* __restrict__ OUT){
  __shared__ short P_lds[4][16][296];
  int tid = threadIdx.x;
  int wid = tid >> 6, lane = tid & 63;
  int lo = lane & 15, hi = lane >> 4;
  int b = blockIdx.x;
  int q0 = blockIdx.y*64 + wid*16;   // q row within h-block [0,NH)

  bf16x8 aq[4];
  size_t qrow = ((size_t)b*NSEQ + MM + q0 + lo)*128;
  #pragma unroll
  for (int ks=0;ks<4;++ks) aq[ks] = *(const bf16x8*)(QB + qrow + ks*32 + hi*8);

  f32x4 s[18];
  #pragma unroll
  for (int nt=0;nt<18;++nt){
    f32x4 acc = {0.f,0.f,0.f,0.f};
    size_t krow = ((size_t)b*NSEQ + nt*16 + lo)*128;
    #pragma unroll
    for (int ks=0;ks<4;++ks){
      bf16x8 bk = *(const bf16x8*)(KB + krow + ks*32 + hi*8);
      acc = __builtin_amdgcn_mfma_f32_16x16x32_bf16(aq[ks], bk, acc, 0,0,0);
    }
    s[nt] = acc;
  }
  if (lo >= 9){
    s[17][0] = -1e30f; s[17][1] = -1e30f; s[17][2] = -1e30f; s[17][3] = -1e30f;
  }
  #pragma unroll
  for (int i=0;i<4;++i){
    float m = -1e30f;
    #pragma unroll
    for (int nt=0;nt<18;++nt) m = fmaxf(m, s[nt][i]);
    #pragma unroll
    for (int d=1; d<16; d<<=1) m = fmaxf(m, __shfl_xor(m, d));
    float ss = 0.f;
    #pragma unroll
    for (int nt=0;nt<18;++nt){ float w = __expf(s[nt][i]-m); s[nt][i] = w; ss += w; }
    #pragma unroll
    for (int d=1; d<16; d<<=1) ss += __shfl_xor(ss, d);
    float rinv = 1.f/ss;
    int r = hi*4 + i;
    #pragma unroll
    for (int nt=0;nt<18;++nt) P_lds[wid][r][nt*16+lo] = f2bf(s[nt][i]*rinv);
  }
  bf16x8 pa[9];
  #pragma unroll
  for (int ks=0;ks<9;++ks) pa[ks] = *(const bf16x8*)&P_lds[wid][lo][ks*32 + hi*8];

  #pragma unroll
  for (int nt=0; nt<8; ++nt){
    f32x4 aoh = {0.f,0.f,0.f,0.f};
    f32x4 axh = {0.f,0.f,0.f,0.f};
    size_t vrow = ((size_t)b*128 + nt*16 + lo)*MPAD;
    #pragma unroll
    for (int ks=0;ks<9;++ks){
      bf16x8 bv = *(const bf16x8*)(VTb + vrow + ks*32 + hi*8);
      aoh = __builtin_amdgcn_mfma_f32_16x16x32_bf16(pa[ks], bv, aoh, 0,0,0);
      bf16x8 bo = *(const bf16x8*)(OPTb + vrow + ks*32 + hi*8);
      axh = __builtin_amdgcn_mfma_f32_16x16x32_bf16(pa[ks], bo, axh, 0,0,0);
    }
    int d = nt*16 + lo;
    short4 o; o.x=f2bf(aoh[0]); o.y=f2bf(aoh[1]); o.z=f2bf(aoh[2]); o.w=f2bf(aoh[3]);
    *(short4*)&OHT[((size_t)b*128 + d)*NH + q0 + hi*4] = o;
    #pragma unroll
    for (int i=0;i<4;++i){
      size_t rq = (size_t)q0 + hi*4 + i;
      size_t oo = ((size_t)b*NSEQ + MM + rq)*128 + d;
      OUT[oo] += axh[i];
    }
  }
}

// ---------------- K5: xp partials = attn_p @ out_h via MFMA (recomputed weights) -------
__global__ __launch_bounds__(64) void k_xp2(const short* __restrict__ QB,
                     const short* __restrict__ KB, const short* __restrict__ OHT,
                     const float* __restrict__ PM, const float* __restrict__ PS,
                     float* __restrict__ PACC){
  __shared__ short P_lds[16][40];
  int lane = threadIdx.x;
  int lo = lane & 15, hi = lane >> 4;
  int mt = blockIdx.x;   // 0..17
  int s  = blockIdx.y;   // 0..NSP-1
  int b  = blockIdx.z;

  bf16x8 aq[4];
  int qrow = mt*16 + lo;
  if (qrow < MM){
    size_t qb = ((size_t)b*NSEQ + qrow)*128;
    #pragma unroll
    for (int ks=0;ks<4;++ks) aq[ks] = *(const bf16x8*)(QB + qb + ks*32 + hi*8);
  } else {
    #pragma unroll
    for (int ks=0;ks<4;++ks) aq[ks] = bf16x8{0,0,0,0,0,0,0,0};
  }

  float M[4], rinv[4];
  #pragma unroll
  for (int i=0;i<4;++i){
    int row = mt*16 + hi*4 + i;
    if (row < MM){ M[i] = PM[(size_t)b*MPAD+row]; rinv[i] = 1.f/PS[(size_t)b*MPAD+row]; }
    else { M[i] = 0.f; rinv[i] = 0.f; }
  }

  f32x4 acc[8];
  #pragma unroll
  for (int nt=0;nt<8;++nt) acc[nt] = f32x4{0.f,0.f,0.f,0.f};

  const int key0 = s*(NH/NSP);
  const size_t kbase = ((size_t)b*NSEQ + MM)*128;
  const size_t obase = (size_t)b*128*NH;

  bf16x8 fr[2][16];
  auto loadFr = [&](int kk, bf16x8* dst){
    #pragma unroll
    for (int t=0;t<2;++t)
      #pragma unroll
      for (int ks=0;ks<4;++ks)
        dst[t*4+ks] = *(const bf16x8*)(KB + kbase + (size_t)(kk + t*16 + lo)*128 + ks*32 + hi*8);
    #pragma unroll
    for (int nt=0;nt<8;++nt)
      dst[8+nt] = *(const bf16x8*)(OHT + obase + (size_t)(nt*16 + lo)*NH + kk + hi*8);
  };

  auto body = [&](bf16x8* cur, bf16x8* nxt, int c, bool pre){
    if (pre) loadFr(key0 + (c+1)*32, nxt);
    f32x4 s0 = {0.f,0.f,0.f,0.f}, s1 = {0.f,0.f,0.f,0.f};
    #pragma unroll
    for (int ks=0;ks<4;++ks){
      s0 = __builtin_amdgcn_mfma_f32_16x16x32_bf16(aq[ks], cur[ks],   s0, 0,0,0);
      s1 = __builtin_amdgcn_mfma_f32_16x16x32_bf16(aq[ks], cur[4+ks], s1, 0,0,0);
    }
    #pragma unroll
    for (int i=0;i<4;++i){
      float p0 = __expf(s0[i]-M[i]), p1 = __expf(s1[i]-M[i]);
      P_lds[hi*4+i][lo]    = f2bf(p0);
      P_lds[hi*4+i][lo+16] = f2bf(p1);
    }
    bf16x8 pa = *(const bf16x8*)&P_lds[lo][hi*8];
    #pragma unroll
    for (int nt=0;nt<8;++nt)
      acc[nt] = __builtin_amdgcn_mfma_f32_16x16x32_bf16(pa, cur[8+nt], acc[nt], 0,0,0);
  };

  loadFr(key0, fr[0]);
  for (int c = 0; c < (NH/NSP)/32; c += 2){
    body(fr[0], fr[1], c,   true);
    body(fr[1], fr[0], c+1, c+2 < (NH/NSP)/32);
  }

  size_t pb = ((size_t)(b*NSP + s)*MPAD + mt*16);
  #pragma unroll
  for (int nt=0;nt<8;++nt)
    #pragma unroll
    for (int i=0;i<4;++i)
      PACC[(pb + hi*4 + i)*128 + nt*16 + lo] = acc[nt][i]*rinv[i];
}

// ---------------- K6: deterministic reduction of xp partials into d_out ----------------
__global__ void k_xpreduce(const float* __restrict__ PACC, float* __restrict__ OUT){
  int b = blockIdx.x, m = blockIdx.y;   // m < 281
  int d = threadIdx.x;
  float a = 0.f;
  #pragma unroll
  for (int s=0;s<NSP;++s) a += PACC[(((size_t)b*NSP+s)*MPAD+m)*128+d];
  OUT[((size_t)b*NSEQ+m)*128+d] += a;
}

extern "C" void kernel_launch(void* const* d_in, const int* in_sizes, int n_in,
                              void* d_out, int out_size, void* d_ws, size_t ws_size,
                              hipStream_t stream){
  const float* x    = (const float*)d_in[0];
  const float* qW   = (const float*)d_in[1];
  const float* qb   = (const float*)d_in[2];
  const float* qA   = (const float*)d_in[3];
  const float* qB   = (const float*)d_in[4];
  const float* kvW  = (const float*)d_in[5];
  const float* kvb  = (const float*)d_in[6];
  const float* kvA  = (const float*)d_in[7];
  const float* kvB  = (const float*)d_in[8];
  const float* resW = (const float*)d_in[9];
  const float* resw = (const float*)d_in[10];
  float* out = (float*)d_out;

  char* base = (char*)d_ws;
  size_t off = 0;
  auto alloc = [&](size_t bytes) -> void* {
    void* p = base + off; off += (bytes + 255) & ~(size_t)255; return p;
  };
  short* WcB  = (short*)alloc(512*256*2);
  float* bc   = (float*)alloc(512*4);
  short* XB   = (short*)alloc((size_t)NTOT*256*2);
  short* QB   = (short*)alloc((size_t)NTOT*128*2);
  short* KB   = (short*)alloc((size_t)NTOT*128*2);
  short* VB   = (short*)alloc((size_t)NTOT*128*2);
  short* VhT  = (short*)alloc((size_t)BB*128*NH*2);
  short* VTb  = (short*)alloc((size_t)BB*128*MPAD*2);
  short* OPTb = (short*)alloc((size_t)BB*128*MPAD*2);
  float* PM   = (float*)alloc((size_t)BB*MPAD*4);
  float* PS   = (float*)alloc((size_t)BB*MPAD*4);
  float* PACC = (float*)alloc((size_t)BB*NSP*MPAD*128*4);
  float* PMX  = (float*)alloc((size_t)BB*NSP*MPAD*4);
  float* PSM  = (float*)alloc((size_t)BB*NSP*MPAD*4);
  short* OHT  = (short*)alloc((size_t)BB*128*NH*2);
  (void)off; (void)ws_size; (void)in_sizes; (void)n_in; (void)out_size;

  k_weights<<<dim3(512), dim3(256), 0, stream>>>(qW,qb,qA,qB,kvW,kvb,kvA,kvB,resW,resw,WcB,bc);
  k_cvtx<<<dim3((int)(((size_t)NTOT*256/8 + 255)/256)), dim3(256), 0, stream>>>(x, XB);
  k_proj3<<<dim3((NTOT+31)/32), dim3(256), 0, stream>>>(XB, WcB, bc, QB, KB, VB, VhT, out);
  k_prep<<<dim3(BB, MPAD), dim3(128), 0, stream>>>(VB, VTb, OPTb);
  k_attnp2<<<dim3(18, NSP, BB), dim3(64), 0, stream>>>(QB, KB, VhT, PACC, PMX, PSM);
  k_pcombine<<<dim3(BB, MM), dim3(128), 0, stream>>>(PACC, PMX, PSM, PM, PS, OPTb);
  k_attnh2<<<dim3(BB, NH/64), dim3(256), 0, stream>>>(QB, KB, VTb, OPTb, OHT, out);
  k_xp2<<<dim3(18, NSP, BB), dim3(64), 0, stream>>>(QB, KB, OHT, PM, PS, PACC);
  k_xpreduce<<<dim3(BB, MM), dim3(128), 0, stream>>>(PACC, out);
}

// Round 6
// 746.402 us; speedup vs baseline: 47.6666x; 1.0498x over previous
//
#include <hip/hip_runtime.h>
#include <hip/hip_bf16.h>
#include <cstddef>

#define MM     281
#define NSEQ   33049
#define BB     4
#define NH     32768          // NSEQ - MM
#define NTOT   (BB*NSEQ)      // 132196
#define MPAD   288
#define NSP    32             // key splits for p-attention
#define SCALEQ 0.125f
#define LORAS  2.0f

typedef __attribute__((ext_vector_type(8))) short bf16x8;
typedef __attribute__((ext_vector_type(4))) float f32x4;

static __device__ __forceinline__ short f2bf(float v){
  __hip_bfloat16 h = __float2bfloat16(v);
  return *reinterpret_cast<short*>(&h);
}

// ---------------- K0: fold LoRA + scales into combined bf16 weight matrix ----------------
__global__ void k_weights(const float* __restrict__ qW, const float* __restrict__ qb,
                          const float* __restrict__ qA, const float* __restrict__ qB,
                          const float* __restrict__ kvW, const float* __restrict__ kvb,
                          const float* __restrict__ kvA, const float* __restrict__ kvB,
                          const float* __restrict__ resW, const float* __restrict__ resw,
                          short* __restrict__ WcB, float* __restrict__ bc){
  int j = blockIdx.x;     // 0..511
  int c = threadIdx.x;    // 0..255
  float w;
  if (j < 128){
    float l = 0.f;
    #pragma unroll
    for (int r = 0; r < 8; ++r) l += qA[j*8+r]*qB[r*256+c];
    w = SCALEQ*(qW[j*256+c] + LORAS*l);
    if (c==0) bc[j] = SCALEQ*qb[j];
  } else if (j < 384){
    int jj = j-128;
    float l = 0.f;
    #pragma unroll
    for (int r = 0; r < 8; ++r) l += kvA[jj*8+r]*kvB[r*256+c];
    w = kvW[jj*256+c] + LORAS*l;
    if (c==0) bc[j] = kvb[jj];
  } else {
    int jj = j-384;
    w = resw[0]*resW[jj*256+c];
    if (c==0) bc[j] = 0.f;
  }
  WcB[j*256+c] = f2bf(w);
}

// ---------------- K0b: X f32 -> bf16 (streaming) ----------------
__global__ __launch_bounds__(256) void k_cvtx(const float* __restrict__ X,
                                              short* __restrict__ XB){
  size_t i = ((size_t)blockIdx.x*256 + threadIdx.x)*8;
  if (i >= (size_t)NTOT*256) return;
  float4 u = *(const float4*)(X+i);
  float4 v = *(const float4*)(X+i+4);
  bf16x8 o = bf16x8{f2bf(u.x),f2bf(u.y),f2bf(u.z),f2bf(u.w),
                    f2bf(v.x),f2bf(v.y),f2bf(v.z),f2bf(v.w)};
  *(bf16x8*)(XB+i) = o;
}

// ---------------- K1: MFMA projection GEMM  Y = xb @ Wc.T + bc ----------------
__global__ __launch_bounds__(256) void k_proj3(const short* __restrict__ XB,
                       const short* __restrict__ WcB, const float* __restrict__ bc,
                       short* __restrict__ QB, short* __restrict__ KB,
                       short* __restrict__ VB, short* __restrict__ VhT,
                       float* __restrict__ OUT){
  int tid = threadIdx.x;
  int wid = tid >> 6, lane = tid & 63;
  int lo = lane & 15, hi = lane >> 4;
  int m0 = blockIdx.x*32;

  f32x4 acc[2][8];
  #pragma unroll
  for (int mt=0;mt<2;++mt)
    #pragma unroll
    for (int nt=0;nt<8;++nt) acc[mt][nt] = f32x4{0.f,0.f,0.f,0.f};

  int r0 = m0 + lo;      if (r0 >= NTOT) r0 = NTOT-1;
  int r1 = m0 + 16 + lo; if (r1 >= NTOT) r1 = NTOT-1;
  const short* x0p = XB + (size_t)r0*256 + hi*8;
  const short* x1p = XB + (size_t)r1*256 + hi*8;

  #pragma unroll
  for (int ks=0; ks<8; ++ks){
    bf16x8 a0 = *(const bf16x8*)(x0p + ks*32);
    bf16x8 a1 = *(const bf16x8*)(x1p + ks*32);
    bf16x8 bfr[8];
    #pragma unroll
    for (int nt=0;nt<8;++nt){
      int jc = wid*128 + nt*16 + lo;
      bfr[nt] = *(const bf16x8*)(WcB + (size_t)jc*256 + ks*32 + hi*8);
    }
    #pragma unroll
    for (int nt=0;nt<8;++nt){
      acc[0][nt] = __builtin_amdgcn_mfma_f32_16x16x32_bf16(a0, bfr[nt], acc[0][nt], 0,0,0);
      acc[1][nt] = __builtin_amdgcn_mfma_f32_16x16x32_bf16(a1, bfr[nt], acc[1][nt], 0,0,0);
    }
  }

  float bias[8];
  #pragma unroll
  for (int nt=0;nt<8;++nt) bias[nt] = bc[wid*128 + nt*16 + lo];

  if (wid == 2){
    #pragma unroll
    for (int mt=0;mt<2;++mt){
      int rbase = m0 + mt*16 + hi*4;
      int b = rbase / NSEQ;
      int m = rbase - b*NSEQ;
      bool fast = (rbase + 3 < NTOT) && (m >= MM) && (m + 4 <= NSEQ);
      #pragma unroll
      for (int nt=0;nt<8;++nt){
        int col = nt*16 + lo;
        float v0 = acc[mt][nt][0]+bias[nt], v1 = acc[mt][nt][1]+bias[nt];
        float v2 = acc[mt][nt][2]+bias[nt], v3 = acc[mt][nt][3]+bias[nt];
        if (fast){
          short4 o; o.x=f2bf(v0); o.y=f2bf(v1); o.z=f2bf(v2); o.w=f2bf(v3);
          *(short4*)&VhT[((size_t)b*128 + col)*NH + (m - MM)] = o;
        } else {
          float vv[4] = {v0,v1,v2,v3};
          #pragma unroll
          for (int i=0;i<4;++i){
            int row = rbase + i;
            if (row >= NTOT) continue;
            int bb = row / NSEQ;
            int mm = row - bb*NSEQ;
            if (mm < MM) VB[((size_t)bb*NSEQ + mm)*128 + col] = f2bf(vv[i]);
            else         VhT[((size_t)bb*128 + col)*NH + (mm - MM)] = f2bf(vv[i]);
          }
        }
      }
    }
  } else {
    #pragma unroll
    for (int mt=0;mt<2;++mt){
      #pragma unroll
      for (int i=0;i<4;++i){
        int row = m0 + mt*16 + hi*4 + i;
        if (row >= NTOT) continue;
        #pragma unroll
        for (int nt=0;nt<8;++nt){
          float v = acc[mt][nt][i] + bias[nt];
          int col = nt*16 + lo;
          if      (wid == 0) QB[(size_t)row*128 + col] = f2bf(v);
          else if (wid == 1) KB[(size_t)row*128 + col] = f2bf(v);
          else               OUT[(size_t)row*128 + col] = v;
        }
      }
    }
  }
}

// ---------------- K1b: V_p^T bf16 (padded) + zero-pad of OP^T tail ----------------
__global__ void k_prep(const short* __restrict__ VB, short* __restrict__ VTb,
                       short* __restrict__ OPTb){
  int b = blockIdx.x, m = blockIdx.y, d = threadIdx.x;  // m<288, d<128
  short vv = (m < MM) ? VB[((size_t)b*NSEQ + m)*128 + d] : (short)0;
  VTb[((size_t)b*128 + d)*MPAD + m] = vv;
  if (m >= MM) OPTb[((size_t)b*128 + d)*MPAD + m] = 0;
}

// ---------------- K2: MFMA flash attn_p partials (split over keys) ----------------
__global__ __launch_bounds__(64) void k_attnp2(const short* __restrict__ QB,
                        const short* __restrict__ KB, const short* __restrict__ VhT,
                        float* __restrict__ PACC, float* __restrict__ PMX,
                        float* __restrict__ PSM){
  __shared__ short P_lds[16][40];
  int lane = threadIdx.x;
  int lo = lane & 15, hi = lane >> 4;
  int mt = blockIdx.x;   // 0..17
  int s  = blockIdx.y;   // 0..NSP-1
  int b  = blockIdx.z;

  bf16x8 aq[4];
  int qrow = mt*16 + lo;
  if (qrow < MM){
    size_t qb = ((size_t)b*NSEQ + qrow)*128;
    #pragma unroll
    for (int ks=0;ks<4;++ks) aq[ks] = *(const bf16x8*)(QB + qb + ks*32 + hi*8);
  } else {
    #pragma unroll
    for (int ks=0;ks<4;++ks) aq[ks] = bf16x8{0,0,0,0,0,0,0,0};
  }

  float rmax[4], rsum[4];
  #pragma unroll
  for (int i=0;i<4;++i){ rmax[i] = -1e30f; rsum[i] = 0.f; }
  f32x4 acc[8];
  #pragma unroll
  for (int nt=0;nt<8;++nt) acc[nt] = f32x4{0.f,0.f,0.f,0.f};

  const int key0 = s*(NH/NSP);            // 1024 keys per split
  const size_t kbase = ((size_t)b*NSEQ + MM)*128;
  const size_t vbase = (size_t)b*128*NH;

  bf16x8 fr[2][16];
  auto loadFr = [&](int kk, bf16x8* dst){
    #pragma unroll
    for (int t=0;t<2;++t)
      #pragma unroll
      for (int ks=0;ks<4;++ks)
        dst[t*4+ks] = *(const bf16x8*)(KB + kbase + (size_t)(kk + t*16 + lo)*128 + ks*32 + hi*8);
    #pragma unroll
    for (int nt=0;nt<8;++nt)
      dst[8+nt] = *(const bf16x8*)(VhT + vbase + (size_t)(nt*16 + lo)*NH + kk + hi*8);
  };

  auto body = [&](bf16x8* cur, bf16x8* nxt, int c, bool pre){
    if (pre) loadFr(key0 + (c+1)*32, nxt);
    f32x4 s0 = {0.f,0.f,0.f,0.f}, s1 = {0.f,0.f,0.f,0.f};
    __builtin_amdgcn_s_setprio(1);
    #pragma unroll
    for (int ks=0;ks<4;++ks){
      s0 = __builtin_amdgcn_mfma_f32_16x16x32_bf16(aq[ks], cur[ks],   s0, 0,0,0);
      s1 = __builtin_amdgcn_mfma_f32_16x16x32_bf16(aq[ks], cur[4+ks], s1, 0,0,0);
    }
    __builtin_amdgcn_s_setprio(0);
    #pragma unroll
    for (int i=0;i<4;++i){
      float mc = fmaxf(s0[i], s1[i]);
      #pragma unroll
      for (int d=1; d<16; d<<=1) mc = fmaxf(mc, __shfl_xor(mc, d));
      float mnew = fmaxf(rmax[i], mc);
      float scale = __expf(rmax[i]-mnew);
      float p0 = __expf(s0[i]-mnew), p1 = __expf(s1[i]-mnew);
      rsum[i] = rsum[i]*scale + p0 + p1;
      rmax[i] = mnew;
      #pragma unroll
      for (int nt=0;nt<8;++nt) acc[nt][i] *= scale;
      P_lds[hi*4+i][lo]    = f2bf(p0);
      P_lds[hi*4+i][lo+16] = f2bf(p1);
    }
    bf16x8 pa = *(const bf16x8*)&P_lds[lo][hi*8];
    __builtin_amdgcn_s_setprio(1);
    #pragma unroll
    for (int nt=0;nt<8;++nt)
      acc[nt] = __builtin_amdgcn_mfma_f32_16x16x32_bf16(pa, cur[8+nt], acc[nt], 0,0,0);
    __builtin_amdgcn_s_setprio(0);
  };

  loadFr(key0, fr[0]);
  for (int c = 0; c < (NH/NSP)/32; c += 2){
    body(fr[0], fr[1], c,   true);
    body(fr[1], fr[0], c+1, c+2 < (NH/NSP)/32);
  }

  #pragma unroll
  for (int i=0;i<4;++i){
    #pragma unroll
    for (int d=1; d<16; d<<=1) rsum[i] += __shfl_xor(rsum[i], d);
  }
  size_t pb = ((size_t)(b*NSP + s)*MPAD + mt*16);
  #pragma unroll
  for (int nt=0;nt<8;++nt)
    #pragma unroll
    for (int i=0;i<4;++i)
      PACC[(pb + hi*4 + i)*128 + nt*16 + lo] = acc[nt][i];
  if (lo == 0){
    #pragma unroll
    for (int i=0;i<4;++i){
      PMX[pb + hi*4 + i] = rmax[i];
      PSM[pb + hi*4 + i] = rsum[i];
    }
  }
}

// ---------------- K3: combine attn_p splits -> OP^T bf16 + final stats ----------------
__global__ void k_pcombine(const float* __restrict__ PACC, const float* __restrict__ PMX,
                           const float* __restrict__ PSM,
                           float* __restrict__ PM, float* __restrict__ PS,
                           short* __restrict__ OPTb){
  int b = blockIdx.x, m = blockIdx.y;   // m < 281
  int d = threadIdx.x;                  // 0..127
  float M = -1e30f;
  #pragma unroll
  for (int s=0;s<NSP;++s) M = fmaxf(M, PMX[((size_t)b*NSP+s)*MPAD+m]);
  float sum = 0.f, a = 0.f;
  #pragma unroll
  for (int s=0;s<NSP;++s){
    size_t pb = ((size_t)b*NSP+s)*MPAD+m;
    float e = __expf(PMX[pb]-M);
    sum += PSM[pb]*e;
    a   += PACC[pb*128+d]*e;
  }
  OPTb[((size_t)b*128+d)*MPAD+m] = f2bf(a/sum);
  if (d==0){ PM[(size_t)b*MPAD+m]=M; PS[(size_t)b*MPAD+m]=sum; }
}

// ---------------- K4: attn_h via MFMA, 2-deep pipelined, deferred normalization -------
__global__ __launch_bounds__(256,4) void k_attnh3(const short* __restrict__ QB,
                        const short* __restrict__ KB,
                        const short* __restrict__ VTb,
                        const short* __restrict__ OPTb,
                        short* __restrict__ OHT, float* __restrict__ OUT){
  __shared__ short P_lds[4][16][296];
  int tid = threadIdx.x;
  int wid = tid >> 6, lane = tid & 63;
  int lo = lane & 15, hi = lane >> 4;
  int b = blockIdx.x;
  int q0 = blockIdx.y*64 + wid*16;   // q row within h-block [0,NH)

  bf16x8 aq[4];
  size_t qrow = ((size_t)b*NSEQ + MM + q0 + lo)*128;
  #pragma unroll
  for (int ks=0;ks<4;++ks) aq[ks] = *(const bf16x8*)(QB + qrow + ks*32 + hi*8);

  // ---- S = Q @ Kp^T, 2-deep prefetch over 18 n-tiles ----
  f32x4 s[18];
  bf16x8 bk[2][4];
  {
    size_t krow0 = ((size_t)b*NSEQ + lo)*128;
    #pragma unroll
    for (int ks=0;ks<4;++ks) bk[0][ks] = *(const bf16x8*)(KB + krow0 + ks*32 + hi*8);
  }
  #pragma unroll
  for (int nt=0;nt<18;++nt){
    int cur = nt&1, nxt = cur^1;
    if (nt < 17){
      size_t krow = ((size_t)b*NSEQ + (nt+1)*16 + lo)*128;
      #pragma unroll
      for (int ks=0;ks<4;++ks) bk[nxt][ks] = *(const bf16x8*)(KB + krow + ks*32 + hi*8);
    }
    f32x4 acc = {0.f,0.f,0.f,0.f};
    __builtin_amdgcn_s_setprio(1);
    #pragma unroll
    for (int ks=0;ks<4;++ks)
      acc = __builtin_amdgcn_mfma_f32_16x16x32_bf16(aq[ks], bk[cur][ks], acc, 0,0,0);
    __builtin_amdgcn_s_setprio(0);
    s[nt] = acc;
  }
  if (lo >= 9){
    s[17][0] = -1e30f; s[17][1] = -1e30f; s[17][2] = -1e30f; s[17][3] = -1e30f;
  }
  // ---- register softmax (unnormalized P; 1/sum deferred to epilogue) ----
  float rinv4[4];
  #pragma unroll
  for (int i=0;i<4;++i){
    float m = -1e30f;
    #pragma unroll
    for (int nt=0;nt<18;++nt) m = fmaxf(m, s[nt][i]);
    #pragma unroll
    for (int d=1; d<16; d<<=1) m = fmaxf(m, __shfl_xor(m, d));
    float ss = 0.f;
    #pragma unroll
    for (int nt=0;nt<18;++nt){ float w = __expf(s[nt][i]-m); s[nt][i] = w; ss += w; }
    #pragma unroll
    for (int d=1; d<16; d<<=1) ss += __shfl_xor(ss, d);
    rinv4[i] = 1.f/ss;
    int r = hi*4 + i;
    #pragma unroll
    for (int nt=0;nt<18;++nt) P_lds[wid][r][nt*16+lo] = f2bf(s[nt][i]);
  }
  bf16x8 pa[9];
  #pragma unroll
  for (int ks=0;ks<9;++ks) pa[ks] = *(const bf16x8*)&P_lds[wid][lo][ks*32 + hi*8];

  // ---- out_h = P@V_p ; xh = P@out_p (2-deep prefetch; OUT rows preloaded) ----
  #pragma unroll
  for (int nt=0; nt<8; ++nt){
    int d = nt*16 + lo;
    const short* pv = VTb  + ((size_t)b*128 + d)*MPAD + hi*8;
    const short* po = OPTb + ((size_t)b*128 + d)*MPAD + hi*8;
    float o4[4];
    #pragma unroll
    for (int i=0;i<4;++i)
      o4[i] = OUT[((size_t)b*NSEQ + MM + q0 + hi*4 + i)*128 + d];
    f32x4 aoh = {0.f,0.f,0.f,0.f};
    f32x4 axh = {0.f,0.f,0.f,0.f};
    bf16x8 bv[2], bo[2];
    bv[0] = *(const bf16x8*)(pv);
    bo[0] = *(const bf16x8*)(po);
    #pragma unroll
    for (int ks=0;ks<9;++ks){
      int cur = ks&1, nxt = cur^1;
      if (ks < 8){
        bv[nxt] = *(const bf16x8*)(pv + (ks+1)*32);
        bo[nxt] = *(const bf16x8*)(po + (ks+1)*32);
      }
      __builtin_amdgcn_s_setprio(1);
      aoh = __builtin_amdgcn_mfma_f32_16x16x32_bf16(pa[ks], bv[cur], aoh, 0,0,0);
      axh = __builtin_amdgcn_mfma_f32_16x16x32_bf16(pa[ks], bo[cur], axh, 0,0,0);
      __builtin_amdgcn_s_setprio(0);
    }
    short4 o;
    o.x = f2bf(aoh[0]*rinv4[0]); o.y = f2bf(aoh[1]*rinv4[1]);
    o.z = f2bf(aoh[2]*rinv4[2]); o.w = f2bf(aoh[3]*rinv4[3]);
    *(short4*)&OHT[((size_t)b*128 + d)*NH + q0 + hi*4] = o;
    #pragma unroll
    for (int i=0;i<4;++i)
      OUT[((size_t)b*NSEQ + MM + q0 + hi*4 + i)*128 + d] = o4[i] + axh[i]*rinv4[i];
  }
}

// ---------------- K5: xp partials = attn_p @ out_h via MFMA (recomputed weights) -------
__global__ __launch_bounds__(64) void k_xp2(const short* __restrict__ QB,
                     const short* __restrict__ KB, const short* __restrict__ OHT,
                     const float* __restrict__ PM, const float* __restrict__ PS,
                     float* __restrict__ PACC){
  __shared__ short P_lds[16][40];
  int lane = threadIdx.x;
  int lo = lane & 15, hi = lane >> 4;
  int mt = blockIdx.x;   // 0..17
  int s  = blockIdx.y;   // 0..NSP-1
  int b  = blockIdx.z;

  bf16x8 aq[4];
  int qrow = mt*16 + lo;
  if (qrow < MM){
    size_t qb = ((size_t)b*NSEQ + qrow)*128;
    #pragma unroll
    for (int ks=0;ks<4;++ks) aq[ks] = *(const bf16x8*)(QB + qb + ks*32 + hi*8);
  } else {
    #pragma unroll
    for (int ks=0;ks<4;++ks) aq[ks] = bf16x8{0,0,0,0,0,0,0,0};
  }

  float M[4], rinv[4];
  #pragma unroll
  for (int i=0;i<4;++i){
    int row = mt*16 + hi*4 + i;
    if (row < MM){ M[i] = PM[(size_t)b*MPAD+row]; rinv[i] = 1.f/PS[(size_t)b*MPAD+row]; }
    else { M[i] = 0.f; rinv[i] = 0.f; }
  }

  f32x4 acc[8];
  #pragma unroll
  for (int nt=0;nt<8;++nt) acc[nt] = f32x4{0.f,0.f,0.f,0.f};

  const int key0 = s*(NH/NSP);
  const size_t kbase = ((size_t)b*NSEQ + MM)*128;
  const size_t obase = (size_t)b*128*NH;

  bf16x8 fr[2][16];
  auto loadFr = [&](int kk, bf16x8* dst){
    #pragma unroll
    for (int t=0;t<2;++t)
      #pragma unroll
      for (int ks=0;ks<4;++ks)
        dst[t*4+ks] = *(const bf16x8*)(KB + kbase + (size_t)(kk + t*16 + lo)*128 + ks*32 + hi*8);
    #pragma unroll
    for (int nt=0;nt<8;++nt)
      dst[8+nt] = *(const bf16x8*)(OHT + obase + (size_t)(nt*16 + lo)*NH + kk + hi*8);
  };

  auto body = [&](bf16x8* cur, bf16x8* nxt, int c, bool pre){
    if (pre) loadFr(key0 + (c+1)*32, nxt);
    f32x4 s0 = {0.f,0.f,0.f,0.f}, s1 = {0.f,0.f,0.f,0.f};
    __builtin_amdgcn_s_setprio(1);
    #pragma unroll
    for (int ks=0;ks<4;++ks){
      s0 = __builtin_amdgcn_mfma_f32_16x16x32_bf16(aq[ks], cur[ks],   s0, 0,0,0);
      s1 = __builtin_amdgcn_mfma_f32_16x16x32_bf16(aq[ks], cur[4+ks], s1, 0,0,0);
    }
    __builtin_amdgcn_s_setprio(0);
    #pragma unroll
    for (int i=0;i<4;++i){
      float p0 = __expf(s0[i]-M[i]), p1 = __expf(s1[i]-M[i]);
      P_lds[hi*4+i][lo]    = f2bf(p0);
      P_lds[hi*4+i][lo+16] = f2bf(p1);
    }
    bf16x8 pa = *(const bf16x8*)&P_lds[lo][hi*8];
    __builtin_amdgcn_s_setprio(1);
    #pragma unroll
    for (int nt=0;nt<8;++nt)
      acc[nt] = __builtin_amdgcn_mfma_f32_16x16x32_bf16(pa, cur[8+nt], acc[nt], 0,0,0);
    __builtin_amdgcn_s_setprio(0);
  };

  loadFr(key0, fr[0]);
  for (int c = 0; c < (NH/NSP)/32; c += 2){
    body(fr[0], fr[1], c,   true);
    body(fr[1], fr[0], c+1, c+2 < (NH/NSP)/32);
  }

  size_t pb = ((size_t)(b*NSP + s)*MPAD + mt*16);
  #pragma unroll
  for (int nt=0;nt<8;++nt)
    #pragma unroll
    for (int i=0;i<4;++i)
      PACC[(pb + hi*4 + i)*128 + nt*16 + lo] = acc[nt][i]*rinv[i];
}

// ---------------- K6: deterministic reduction of xp partials into d_out ----------------
__global__ void k_xpreduce(const float* __restrict__ PACC, float* __restrict__ OUT){
  int b = blockIdx.x, m = blockIdx.y;   // m < 281
  int d = threadIdx.x;
  float a = 0.f;
  #pragma unroll
  for (int s=0;s<NSP;++s) a += PACC[(((size_t)b*NSP+s)*MPAD+m)*128+d];
  OUT[((size_t)b*NSEQ+m)*128+d] += a;
}

extern "C" void kernel_launch(void* const* d_in, const int* in_sizes, int n_in,
                              void* d_out, int out_size, void* d_ws, size_t ws_size,
                              hipStream_t stream){
  const float* x    = (const float*)d_in[0];
  const float* qW   = (const float*)d_in[1];
  const float* qb   = (const float*)d_in[2];
  const float* qA   = (const float*)d_in[3];
  const float* qB   = (const float*)d_in[4];
  const float* kvW  = (const float*)d_in[5];
  const float* kvb  = (const float*)d_in[6];
  const float* kvA  = (const float*)d_in[7];
  const float* kvB  = (const float*)d_in[8];
  const float* resW = (const float*)d_in[9];
  const float* resw = (const float*)d_in[10];
  float* out = (float*)d_out;

  char* base = (char*)d_ws;
  size_t off = 0;
  auto alloc = [&](size_t bytes) -> void* {
    void* p = base + off; off += (bytes + 255) & ~(size_t)255; return p;
  };
  short* WcB  = (short*)alloc(512*256*2);
  float* bc   = (float*)alloc(512*4);
  short* XB   = (short*)alloc((size_t)NTOT*256*2);
  short* QB   = (short*)alloc((size_t)NTOT*128*2);
  short* KB   = (short*)alloc((size_t)NTOT*128*2);
  short* VB   = (short*)alloc((size_t)NTOT*128*2);
  short* VhT  = (short*)alloc((size_t)BB*128*NH*2);
  short* VTb  = (short*)alloc((size_t)BB*128*MPAD*2);
  short* OPTb = (short*)alloc((size_t)BB*128*MPAD*2);
  float* PM   = (float*)alloc((size_t)BB*MPAD*4);
  float* PS   = (float*)alloc((size_t)BB*MPAD*4);
  float* PACC = (float*)alloc((size_t)BB*NSP*MPAD*128*4);
  float* PMX  = (float*)alloc((size_t)BB*NSP*MPAD*4);
  float* PSM  = (float*)alloc((size_t)BB*NSP*MPAD*4);
  short* OHT  = (short*)alloc((size_t)BB*128*NH*2);
  (void)off; (void)ws_size; (void)in_sizes; (void)n_in; (void)out_size;

  k_weights<<<dim3(512), dim3(256), 0, stream>>>(qW,qb,qA,qB,kvW,kvb,kvA,kvB,resW,resw,WcB,bc);
  k_cvtx<<<dim3((int)(((size_t)NTOT*256/8 + 255)/256)), dim3(256), 0, stream>>>(x, XB);
  k_proj3<<<dim3((NTOT+31)/32), dim3(256), 0, stream>>>(XB, WcB, bc, QB, KB, VB, VhT, out);
  k_prep<<<dim3(BB, MPAD), dim3(128), 0, stream>>>(VB, VTb, OPTb);
  k_attnp2<<<dim3(18, NSP, BB), dim3(64), 0, stream>>>(QB, KB, VhT, PACC, PMX, PSM);
  k_pcombine<<<dim3(BB, MM), dim3(128), 0, stream>>>(PACC, PMX, PSM, PM, PS, OPTb);
  k_attnh3<<<dim3(BB, NH/64), dim3(256), 0, stream>>>(QB, KB, VTb, OPTb, OHT, out);
  k_xp2<<<dim3(18, NSP, BB), dim3(64), 0, stream>>>(QB, KB, OHT, PM, PS, PACC);
  k_xpreduce<<<dim3(BB, MM), dim3(128), 0, stream>>>(PACC, out);
}